// Round 12
// baseline (367.345 us; speedup 1.0000x reference)
//
#include <hip/hip_runtime.h>
#include <hip/hip_bf16.h>
#include <math.h>

#define NN   10000
#define IND  512
#define HID  256
#define NE   400000
#define KPAD 10240   // adj GEMM K padded (320 panels of 32)
#define SKA  8       // adj split-K: k_chunk 1280, nt 40
#define KCHA 1280
#define BM   128
#define NBIN 10240   // histogram bins (>= NN, = 256*40)

typedef __attribute__((ext_vector_type(4))) float  f32x4;
typedef __attribute__((ext_vector_type(4))) int    i32x4;
typedef __attribute__((ext_vector_type(2))) uint   u32x2;
typedef __attribute__((ext_vector_type(8))) short  bf16x8;

static __device__ inline ushort f2b(float f) {
    union { __hip_bfloat16 b; ushort u; } c;
    c.b = __float2bfloat16(f);
    return c.u;
}
static __device__ inline float b2f(ushort u) {
    union { uint t; float f; } c;
    c.t = (uint)u << 16;
    return c.f;
}
static __device__ inline void gload_lds16(const void* g, void* l) {
    __builtin_amdgcn_global_load_lds(
        (const __attribute__((address_space(1))) unsigned int*)g,
        (__attribute__((address_space(3))) unsigned int*)l, 16, 0, 0);
}
// pinned-order A prefetch: exactly 2 vmem loads (vmcnt accounting)
static __device__ inline void aload(const float* p, f32x4& a, f32x4& b) {
    asm volatile("global_load_dwordx4 %0, %2, off\n\t"
                 "global_load_dwordx4 %1, %2, off offset:16"
                 : "=&v"(a), "=&v"(b) : "v"(p) : "memory");
}

// ---------------------------------------------------------------------------
// W -> K-step panels (16 KB each), panel linear order == GEMM LDS frag order:
//   slot s (16 B): g = s>>6, l = s&63 -> B[col = g*16 + (l&15)][k8 = l>>4]
__global__ __launch_bounds__(256) void cvt_tiled(
    const float* __restrict__ src, ushort* __restrict__ dst, int R)
{
    __shared__ float t[32][256];
    const int p   = blockIdx.x;
    const int tid = threadIdx.x;
    const int r0  = p << 5;

    #pragma unroll
    for (int j = 0; j < 8; ++j) {
        const int f   = (j << 8) + tid;
        const int row = f >> 6;
        const int c4  = (f & 63) << 2;
        f32x4 v = {0.f, 0.f, 0.f, 0.f};
        if (r0 + row < R)
            v = *reinterpret_cast<const f32x4*>(&src[(size_t)(r0 + row) * 256 + c4]);
        *reinterpret_cast<f32x4*>(&t[row][c4]) = v;
    }
    __syncthreads();

    #pragma unroll
    for (int qq = 0; qq < 4; ++qq) {
        const int s   = (qq << 8) + tid;
        const int g   = s >> 6, l = s & 63;
        const int col = (g << 4) + (l & 15);
        const int k8  = (l >> 4) << 3;
        union { ushort u[8]; i32x4 v4; } pk;
        #pragma unroll
        for (int i = 0; i < 8; ++i) pk.u[i] = f2b(t[k8 + i][col]);
        *reinterpret_cast<i32x4*>(&dst[((size_t)p << 13) + ((size_t)s << 3)]) = pk.v4;
    }
}

// ---------------------------------------------------------------------------
// PANEL=false: Cpart[sk][M,256] bf16 = A[M, chunk] @ B(chunk), direct store.
// PANEL=true : Cout = bf16 K-step panels of (A @ B) (fused cvt_tiled), sk==0;
//              grid covers ceil(KPAD/128) row tiles so pad panels emit zeros.
// A f32 (cvt bf16 on the fly, reg->LDS dbuf), B pre-tiled bf16 panels staged
// 2 steps ahead into a ring-3 LDS buffer via contiguous 1 KB global_load_lds.
// 128x256 block, 8 waves (2x4), wave tile 64x64, BK=32. Per step exactly one
// "s_waitcnt vmcnt(4)" (drains B(t+1)+A(t+1), both issued a full step earlier)
// + lgkmcnt(0) + barrier. No mid-loop drain; tail drains vmcnt(0).
template<bool PANEL>
__global__ __launch_bounds__(512, 4) void gemm_bt(
    const float* __restrict__ A, const ushort* __restrict__ BT2,
    void* __restrict__ Cout, int M, int K_real, int lda, int k_chunk,
    size_t c_stride)
{
    __shared__ ushort Alds[2][4096];   // 16 KB (A dbuf)
    __shared__ ushort Blds[3][8192];   // 48 KB (B ring-3)

    const int tid  = threadIdx.x;      // 0..511
    const int lane = tid & 63;
    const int w    = tid >> 6;         // wave 0..7
    const int wm   = w >> 2;           // row half
    const int wn   = w & 3;            // col quadrant

    // bijective XCD-chunk swizzle; row fastest, sk-major
    const int gx  = gridDim.x;
    const int nwg = gx * gridDim.y;
    const int lin = blockIdx.y * gx + blockIdx.x;
    const int q = nwg >> 3, r = nwg & 7;
    const int xc = lin & 7, o = lin >> 3;
    const int work = (xc < r ? xc * (q + 1) : r * (q + 1) + (xc - r) * q) + o;
    const int row0 = (work % gx) * BM;
    const int sk   = work / gx;
    const int kbeg = sk * k_chunk;

    // A staging: thread t -> (row t>>2, kgroup t&3); LDS slot = inverse frag map
    const int arow = tid >> 2;
    const int akg  = tid & 3;
    const int grow = row0 + arow;
    const bool aok = grow < M;
    const bool lastrow = (grow == M - 1);
    const float* aptr = A + (size_t)grow * lda + kbeg + (akg << 3);
    const int aslot = ((arow >> 4) << 6) | (akg << 4) | (arow & 15);

    const int nt = k_chunk >> 5;       // 40 or 16 (even, >= 3)

    f32x4 acc[4][4];
    #pragma unroll
    for (int i = 0; i < 4; ++i)
        #pragma unroll
        for (int j = 0; j < 4; ++j)
            acc[i][j] = (f32x4){0.f, 0.f, 0.f, 0.f};

    auto apick = [&](int kn) -> const float* {
        const bool ok = aok && (kn < k_chunk) &&
                        (!lastrow || (kbeg + kn + (akg << 3) + 8) <= K_real);
        return ok ? (aptr + kn) : A;
    };
    // stage B panel tile tt into ring slot tt%3: 2 contiguous 1 KB gloads/wave
    auto stageB = [&](int tt) {
        const int slot = tt % 3;
        const ushort* ps = BT2 + (((size_t)(kbeg >> 5) + tt) << 13) + ((w << 1) << 9);
        gload_lds16(ps,       &Blds[slot][(w << 1) << 9]);
        gload_lds16(ps + 512, &Blds[slot][((w << 1) + 1) << 9]);
    };
    auto writeA = [&](int buf, const f32x4& x0, const f32x4& x1) {
        union { ushort u[8]; i32x4 v4; } pk;
        pk.u[0]=f2b(x0.x); pk.u[1]=f2b(x0.y); pk.u[2]=f2b(x0.z); pk.u[3]=f2b(x0.w);
        pk.u[4]=f2b(x1.x); pk.u[5]=f2b(x1.y); pk.u[6]=f2b(x1.z); pk.u[7]=f2b(x1.w);
        *reinterpret_cast<i32x4*>(&Alds[buf][aslot << 3]) = pk.v4;
    };
    auto compute = [&](int tt) {
        const ushort* Bb = Blds[tt % 3];
        const ushort* Ab = Alds[tt & 1];
        bf16x8 bfr[4];
        #pragma unroll
        for (int nf = 0; nf < 4; ++nf)
            bfr[nf] = *reinterpret_cast<const bf16x8*>(
                &Bb[((((wn << 2) + nf) << 6) | lane) << 3]);
        #pragma unroll
        for (int mf = 0; mf < 4; ++mf) {
            const bf16x8 af = *reinterpret_cast<const bf16x8*>(
                &Ab[((((wm << 2) + mf) << 6) | lane) << 3]);
            #pragma unroll
            for (int nf = 0; nf < 4; ++nf)
                acc[mf][nf] = __builtin_amdgcn_mfma_f32_16x16x32_bf16(
                    af, bfr[nf], acc[mf][nf], 0, 0, 0);
        }
    };

    f32x4 aP0, aP1, aQ0, aQ1;
    // steady step t: stage B(t+2), load A(t+2); compute(t); end-wait drains
    // B(t+1)+A(t+1) (issued in step t-1; queue order B-then-A => vmcnt(4)).
    auto STEP = [&](int t, f32x4& c0, f32x4& c1, f32x4& n0, f32x4& n1) {
        stageB(t + 2);
        aload(apick((t + 2) << 5), n0, n1);
        compute(t);
        asm volatile("s_waitcnt vmcnt(4)" ::: "memory");
        __builtin_amdgcn_sched_barrier(0);
        writeA((t + 1) & 1, c0, c1);
        asm volatile("s_waitcnt lgkmcnt(0)" ::: "memory");
        __builtin_amdgcn_s_barrier();
    };

    // ---- prologue: queue = [B0, B1, A0, A1]; drain B0,B1,A0 ----
    stageB(0);
    stageB(1);
    aload(apick(0),  aP0, aP1);
    aload(apick(32), aQ0, aQ1);
    asm volatile("s_waitcnt vmcnt(2)" ::: "memory");
    __builtin_amdgcn_sched_barrier(0);
    writeA(0, aP0, aP1);
    asm volatile("s_waitcnt lgkmcnt(0)" ::: "memory");
    __builtin_amdgcn_s_barrier();

    // ---- main: steps t = 0 .. nt-3 (manual 2-unroll, static reg parity) ----
    int t = 0;
    for (; t + 1 < nt - 2; t += 2) {
        STEP(t,     aQ0, aQ1, aP0, aP1);
        STEP(t + 1, aP0, aP1, aQ0, aQ1);
    }
    bool lastInP = false;
    if (t < nt - 2) { STEP(t, aQ0, aQ1, aP0, aP1); lastInP = true; }

    // ---- tail: tiles nt-2 and nt-1 (everything already in flight) ----
    compute(nt - 2);
    asm volatile("s_waitcnt vmcnt(0)" ::: "memory");   // B(nt-1), A(nt-1) landed
    __builtin_amdgcn_sched_barrier(0);
    if (lastInP) writeA((nt - 1) & 1, aP0, aP1);
    else         writeA((nt - 1) & 1, aQ0, aQ1);
    asm volatile("s_waitcnt lgkmcnt(0)" ::: "memory");
    __builtin_amdgcn_s_barrier();
    compute(nt - 1);

    if constexpr (!PANEL) {
        // bf16 partial store; col = lane&15, row = (lane>>4)*4 + rr
        ushort* C = (ushort*)Cout + (size_t)sk * c_stride;
        #pragma unroll
        for (int mf = 0; mf < 4; ++mf) {
            const int rbase = row0 + (wm << 6) + mf * 16 + ((lane >> 4) << 2);
            #pragma unroll
            for (int nf = 0; nf < 4; ++nf) {
                const int col = (wn << 6) + nf * 16 + (lane & 15);
                #pragma unroll
                for (int rr = 0; rr < 4; ++rr) {
                    const int row = rbase + rr;
                    if (row < M) C[(size_t)row * HID + col] = f2b(acc[mf][nf][rr]);
                }
            }
        }
    } else {
        // bf16 panel store via LDS re-layout; block covers panels (row0>>5)+0..3
        // (rows >= M emit zeros -> pad panels are written by the tail block).
        // Lp = ring slot nt%3: last read at compute(nt-3), >=1 barrier ago.
        ushort* Cp = (ushort*)Cout;
        ushort* Lp = Blds[nt % 3];
        #pragma unroll
        for (int pp = 0; pp < 4; ++pp) {
            if ((w >> 2) == (pp >> 1)) {
                #pragma unroll
                for (int mfh = 0; mfh < 2; ++mfh) {
                    const int mf = ((pp & 1) << 1) + mfh;
                    const int kb = (mfh << 4) + ((lane >> 4) << 2);  // 0..28
                    #pragma unroll
                    for (int nf = 0; nf < 4; ++nf) {
                        const int col = (wn << 6) + (nf << 4) + (lane & 15);
                        const int s = ((col >> 4) << 6) | ((kb >> 3) << 4) | (col & 15);
                        union { ushort u[4]; u32x2 v; } pk;
                        #pragma unroll
                        for (int rr = 0; rr < 4; ++rr) {
                            const int row = row0 + (pp << 5) + kb + rr;
                            pk.u[rr] = (row < M) ? f2b(acc[mf][nf][rr]) : (ushort)0;
                        }
                        *reinterpret_cast<u32x2*>(&Lp[(s << 3) + (kb & 7)]) = pk.v;
                    }
                }
            }
            __syncthreads();
            const size_t P = (size_t)((row0 >> 5) + pp);
            const ushort* sp = &Lp[tid << 4];
            ushort* gp = Cp + (P << 13) + ((size_t)tid << 4);
            *reinterpret_cast<i32x4*>(gp)     = *reinterpret_cast<const i32x4*>(sp);
            *reinterpret_cast<i32x4*>(gp + 8) = *reinterpret_cast<const i32x4*>(sp + 8);
            __syncthreads();
        }
    }
}

// ---------------------------------------------------------------------------
// Fused prep: zero cnt[NBIN]; first 512 threads also compute c[j]=W2[j,:]·W3
__global__ __launch_bounds__(256) void k_prep(
    const float* __restrict__ W2, const float* __restrict__ W3,
    float* __restrict__ c, int* __restrict__ cnt)
{
    const int gid = blockIdx.x * 256 + threadIdx.x;
    if (gid < NBIN) cnt[gid] = 0;
    if (gid < 2 * HID) {
        float s = 0.f;
        for (int m = 0; m < HID; ++m)
            s = fmaf(W2[(size_t)gid * HID + m], W3[m], s);
        c[gid] = s;
    }
}

// histogram of source nodes over both edge lists
__global__ __launch_bounds__(256) void k_hist(
    const int* __restrict__ e1, const int* __restrict__ e2,
    int* __restrict__ cnt)
{
    const int e = blockIdx.x * 256 + threadIdx.x;
    if (e >= 2 * NE) return;
    const int2 p = (e < NE) ? ((const int2*)e1)[e] : ((const int2*)e2)[e - NE];
    atomicAdd(&cnt[p.x], 1);
}

// exclusive prefix sum of cnt[NBIN] -> off[NBIN]; one block of 256 threads
__global__ __launch_bounds__(256) void k_scan(
    const int* __restrict__ cnt, int* __restrict__ off)
{
    __shared__ int ps[256];
    const int tid = threadIdx.x;
    int local[40];
    int s = 0;
    #pragma unroll
    for (int k = 0; k < 40; ++k) { local[k] = cnt[tid * 40 + k]; s += local[k]; }
    ps[tid] = s;
    __syncthreads();
    for (int d = 1; d < 256; d <<= 1) {
        const int v = (tid >= d) ? ps[tid - d] : 0;
        __syncthreads();
        ps[tid] += v;
        __syncthreads();
    }
    int run = ps[tid] - s;   // exclusive base for this thread's 40 bins
    #pragma unroll
    for (int k = 0; k < 40; ++k) { off[tid * 40 + k] = run; run += local[k]; }
}

// scatter edges into i-sorted order: sij[pos] = (i<<14)|j, eid[pos] = e
__global__ __launch_bounds__(256) void k_scatter(
    const int* __restrict__ e1, const int* __restrict__ e2,
    int* __restrict__ off, int* __restrict__ sij, int* __restrict__ eid)
{
    const int e = blockIdx.x * 256 + threadIdx.x;
    if (e >= 2 * NE) return;
    const int2 p = (e < NE) ? ((const int2*)e1)[e] : ((const int2*)e2)[e - NE];
    const int pos = atomicAdd(&off[p.x], 1);
    sij[pos] = (p.x << 14) | p.y;
    eid[pos] = e;
}

// ---------------------------------------------------------------------------
// Reduce SKA bf16 partials -> z (f32); write bf16 z table; a,b scalars
__global__ __launch_bounds__(256) void k_node(
    const ushort* __restrict__ Cpart, const float* __restrict__ c,
    ushort* __restrict__ zb, float* __restrict__ av, float* __restrict__ bv)
{
    const int node = (int)((blockIdx.x * blockDim.x + threadIdx.x) >> 6);
    const int lane = threadIdx.x & 63;
    if (node >= NN) return;

    const ushort* p0 = Cpart + (size_t)node * HID + (lane << 2);
    f32x4 s = {0.f, 0.f, 0.f, 0.f};
    #pragma unroll
    for (int p = 0; p < SKA; ++p) {
        union { u32x2 v; ushort u[4]; } raw;
        raw.v = *reinterpret_cast<const u32x2*>(p0 + (size_t)p * NN * HID);
        s.x += b2f(raw.u[0]); s.y += b2f(raw.u[1]);
        s.z += b2f(raw.u[2]); s.w += b2f(raw.u[3]);
    }

    const f32x4 u4 = *reinterpret_cast<const f32x4*>(&c[(lane << 2)]);
    const f32x4 v4 = *reinterpret_cast<const f32x4*>(&c[HID + (lane << 2)]);

    union { ushort u[4]; u32x2 v; } pz;
    pz.u[0] = f2b(s.x); pz.u[1] = f2b(s.y);
    pz.u[2] = f2b(s.z); pz.u[3] = f2b(s.w);
    *reinterpret_cast<u32x2*>(&zb[(size_t)node * HID + (lane << 2)]) = pz.v;

    const float r0 = fmaxf(s.x, 0.f), r1 = fmaxf(s.y, 0.f);
    const float r2 = fmaxf(s.z, 0.f), r3 = fmaxf(s.w, 0.f);
    float pa = r0 * u4.x + r1 * u4.y + r2 * u4.z + r3 * u4.w;
    float pb = r0 * v4.x + r1 * v4.y + r2 * v4.z + r3 * v4.w;

    #pragma unroll
    for (int off = 32; off; off >>= 1) {
        pa += __shfl_down(pa, off);
        pb += __shfl_down(pb, off);
    }
    if (lane == 0) { av[node] = pa; bv[node] = pb; }
}

// ---------------------------------------------------------------------------
// 4 sorted edges per wave (16 lanes each); consecutive slots share i -> zi
// row is L1/L2-hot. out[eid] = sigmoid(a[i]+b[j]+sum z_i z_j w3b).
__global__ __launch_bounds__(256) void k_edge2(
    const int* __restrict__ sij, const int* __restrict__ eid,
    const ushort* __restrict__ zb, const float* __restrict__ av,
    const float* __restrict__ bv, const float* __restrict__ W3,
    float* __restrict__ out)
{
    const long long t = (((long long)blockIdx.x * blockDim.x) + threadIdx.x) >> 4;
    const int s16 = threadIdx.x & 15;
    if (t >= 2LL * NE) return;

    // per-lane w3b slice (16 f32, held in VGPRs)
    const float* w3p = W3 + HID + (s16 << 4);
    f32x4 wv[4];
    #pragma unroll
    for (int i = 0; i < 4; ++i)
        wv[i] = *reinterpret_cast<const f32x4*>(w3p + (i << 2));

    const int pk = sij[t];
    const int i = pk >> 14;
    const int j = pk & 16383;

    const ushort* zi = &zb[(size_t)i * HID + (s16 << 4)];
    const ushort* zj = &zb[(size_t)j * HID + (s16 << 4)];
    const bf16x8 zi0 = *reinterpret_cast<const bf16x8*>(zi);
    const bf16x8 zi1 = *reinterpret_cast<const bf16x8*>(zi + 8);
    const bf16x8 zj0 = *reinterpret_cast<const bf16x8*>(zj);
    const bf16x8 zj1 = *reinterpret_cast<const bf16x8*>(zj + 8);

    float p = 0.f;
    #pragma unroll
    for (int tt = 0; tt < 8; ++tt)
        p = fmaf(b2f((ushort)zi0[tt]) * b2f((ushort)zj0[tt]), wv[tt >> 2][tt & 3], p);
    #pragma unroll
    for (int tt = 0; tt < 8; ++tt)
        p = fmaf(b2f((ushort)zi1[tt]) * b2f((ushort)zj1[tt]), wv[2 + (tt >> 2)][tt & 3], p);

    #pragma unroll
    for (int m = 8; m; m >>= 1)
        p += __shfl_xor(p, m);

    if (s16 == 0) {
        const float logit = av[i] + bv[j] + p;
        out[eid[t]] = 1.f / (1.f + expf(-logit));
    }
}

// ---------------------------------------------------------------------------
extern "C" void kernel_launch(void* const* d_in, const int* in_sizes, int n_in,
                              void* d_out, int out_size, void* d_ws, size_t ws_size,
                              hipStream_t stream)
{
    const float* X   = (const float*)d_in[0];
    const float* adj = (const float*)d_in[1];
    const int*   e1  = (const int*)d_in[2];
    const int*   e2  = (const int*)d_in[3];
    const float* W   = (const float*)d_in[4];
    const float* W2  = (const float*)d_in[5];
    const float* W3  = (const float*)d_in[6];
    float* out = (float*)d_out;

    float*  ws    = (float*)d_ws;
    float*  a     = ws;                                  // NN
    float*  b     = a + NN;                              // NN
    float*  c     = b + NN;                              // 512
    int*    cnt   = (int*)(c + 512);                     // NBIN
    int*    soff  = cnt + NBIN;                          // NBIN
    int*    sij   = soff + NBIN;                         // 2*NE
    int*    eid   = sij + 2 * NE;                        // 2*NE
    ushort* Wt2   = (ushort*)(eid + 2 * NE);             // 16 panels * 8192
    ushort* XWt2  = Wt2  + (size_t)16 * 8192;            // 320 panels * 8192
    ushort* zb    = XWt2 + (size_t)320 * 8192;           // NN*HID
    ushort* Cpart = zb + (size_t)NN * HID;               // SKA*NN*HID bf16

    const dim3 blk(256);

    // prep: zero histogram + c = [u; v]
    k_prep<<<dim3(NBIN / 256), blk, 0, stream>>>(W2, W3, c, cnt);

    // edge counting sort by source node
    k_hist<<<dim3((2 * NE + 255) / 256), blk, 0, stream>>>(e1, e2, cnt);
    k_scan<<<dim3(1), blk, 0, stream>>>(cnt, soff);
    k_scatter<<<dim3((2 * NE + 255) / 256), blk, 0, stream>>>(e1, e2, soff, sij, eid);

    // W -> tiled bf16 panels (K=512 -> 16 panels)
    cvt_tiled<<<dim3(16), blk, 0, stream>>>(W, Wt2, IND);

    // XW panels = X @ W, fused panel epilogue; grid 80 also writes pad panels
    gemm_bt<true><<<dim3(80, 1), dim3(512), 0, stream>>>(
        X, Wt2, XWt2, NN, IND, IND, IND, 0);

    // Cpart = adj @ XW  (split-K = 8, direct bf16 store)
    gemm_bt<false><<<dim3(79, SKA), dim3(512), 0, stream>>>(
        adj, XWt2, Cpart, NN, NN, NN, KCHA, (size_t)NN * HID);

    // reduce bf16 partials + z table + a,b
    k_node<<<dim3((NN * 64) / 256), blk, 0, stream>>>(Cpart, c, zb, a, b);

    // per-edge output over sorted edges (4 edges / wave)
    k_edge2<<<dim3((2 * NE * 16) / 256), blk, 0, stream>>>(
        sij, eid, zb, a, b, W3, out);
}

// Round 13
// 261.747 us; speedup vs baseline: 1.4034x; 1.4034x over previous
//
#include <hip/hip_runtime.h>
#include <hip/hip_bf16.h>
#include <math.h>

#define NN   10000
#define IND  512
#define HID  256
#define NE   400000
#define KPAD 10240   // adj GEMM K padded (320 panels of 32)
#define SKA  8       // adj split-K: k_chunk 1280, nt 40
#define KCHA 1280
#define BM   128

typedef __attribute__((ext_vector_type(4))) float  f32x4;
typedef __attribute__((ext_vector_type(4))) int    i32x4;
typedef __attribute__((ext_vector_type(2))) uint   u32x2;
typedef __attribute__((ext_vector_type(8))) short  bf16x8;

static __device__ inline ushort f2b(float f) {
    union { __hip_bfloat16 b; ushort u; } c;
    c.b = __float2bfloat16(f);
    return c.u;
}
static __device__ inline float b2f(ushort u) {
    union { uint t; float f; } c;
    c.t = (uint)u << 16;
    return c.f;
}
static __device__ inline void gload_lds16(const void* g, void* l) {
    __builtin_amdgcn_global_load_lds(
        (const __attribute__((address_space(1))) unsigned int*)g,
        (__attribute__((address_space(3))) unsigned int*)l, 16, 0, 0);
}
// pinned-order A prefetch: exactly 2 vmem loads (vmcnt accounting)
static __device__ inline void aload(const float* p, f32x4& a, f32x4& b) {
    asm volatile("global_load_dwordx4 %0, %2, off\n\t"
                 "global_load_dwordx4 %1, %2, off offset:16"
                 : "=&v"(a), "=&v"(b) : "v"(p) : "memory");
}

// ---------------------------------------------------------------------------
// W -> K-step panels (16 KB each), panel linear order == GEMM LDS frag order:
//   slot s (16 B): g = s>>6, l = s&63 -> B[col = g*16 + (l&15)][k8 = l>>4]
__global__ __launch_bounds__(256) void cvt_tiled(
    const float* __restrict__ src, ushort* __restrict__ dst, int R)
{
    __shared__ float t[32][256];
    const int p   = blockIdx.x;
    const int tid = threadIdx.x;
    const int r0  = p << 5;

    #pragma unroll
    for (int j = 0; j < 8; ++j) {
        const int f   = (j << 8) + tid;
        const int row = f >> 6;
        const int c4  = (f & 63) << 2;
        f32x4 v = {0.f, 0.f, 0.f, 0.f};
        if (r0 + row < R)
            v = *reinterpret_cast<const f32x4*>(&src[(size_t)(r0 + row) * 256 + c4]);
        *reinterpret_cast<f32x4*>(&t[row][c4]) = v;
    }
    __syncthreads();

    #pragma unroll
    for (int qq = 0; qq < 4; ++qq) {
        const int s   = (qq << 8) + tid;
        const int g   = s >> 6, l = s & 63;
        const int col = (g << 4) + (l & 15);
        const int k8  = (l >> 4) << 3;
        union { ushort u[8]; i32x4 v4; } pk;
        #pragma unroll
        for (int i = 0; i < 8; ++i) pk.u[i] = f2b(t[k8 + i][col]);
        *reinterpret_cast<i32x4*>(&dst[((size_t)p << 13) + ((size_t)s << 3)]) = pk.v4;
    }
}

// ---------------------------------------------------------------------------
// PANEL=false: Cpart[sk][M,256] bf16 = A[M, chunk] @ B(chunk), direct store.
// PANEL=true : Cout = bf16 K-step panels of (A @ B) (fused cvt_tiled), sk==0;
//              grid covers ceil(KPAD/128) row tiles so pad panels emit zeros.
// A f32 (cvt bf16 on the fly, reg->LDS dbuf), B pre-tiled bf16 panels staged
// 2 steps ahead into a ring-3 LDS buffer via contiguous 1 KB global_load_lds.
// 128x256 block, 8 waves (2x4), wave tile 64x64, BK=32. Per step exactly one
// "s_waitcnt vmcnt(4)" (drains B(t+1)+A(t+1), both issued a full step earlier)
// + lgkmcnt(0) + barrier. No mid-loop drain; tail drains vmcnt(0).
template<bool PANEL>
__global__ __launch_bounds__(512, 4) void gemm_bt(
    const float* __restrict__ A, const ushort* __restrict__ BT2,
    void* __restrict__ Cout, int M, int K_real, int lda, int k_chunk,
    size_t c_stride)
{
    __shared__ ushort Alds[2][4096];   // 16 KB (A dbuf)
    __shared__ ushort Blds[3][8192];   // 48 KB (B ring-3)

    const int tid  = threadIdx.x;      // 0..511
    const int lane = tid & 63;
    const int w    = tid >> 6;         // wave 0..7
    const int wm   = w >> 2;           // row half
    const int wn   = w & 3;            // col quadrant

    // bijective XCD-chunk swizzle; row fastest, sk-major
    const int gx  = gridDim.x;
    const int nwg = gx * gridDim.y;
    const int lin = blockIdx.y * gx + blockIdx.x;
    const int q = nwg >> 3, r = nwg & 7;
    const int xc = lin & 7, o = lin >> 3;
    const int work = (xc < r ? xc * (q + 1) : r * (q + 1) + (xc - r) * q) + o;
    const int row0 = (work % gx) * BM;
    const int sk   = work / gx;
    const int kbeg = sk * k_chunk;

    // A staging: thread t -> (row t>>2, kgroup t&3); LDS slot = inverse frag map
    const int arow = tid >> 2;
    const int akg  = tid & 3;
    const int grow = row0 + arow;
    const bool aok = grow < M;
    const bool lastrow = (grow == M - 1);
    const float* aptr = A + (size_t)grow * lda + kbeg + (akg << 3);
    const int aslot = ((arow >> 4) << 6) | (akg << 4) | (arow & 15);

    const int nt = k_chunk >> 5;       // 40 or 16 (even, >= 3)

    f32x4 acc[4][4];
    #pragma unroll
    for (int i = 0; i < 4; ++i)
        #pragma unroll
        for (int j = 0; j < 4; ++j)
            acc[i][j] = (f32x4){0.f, 0.f, 0.f, 0.f};

    auto apick = [&](int kn) -> const float* {
        const bool ok = aok && (kn < k_chunk) &&
                        (!lastrow || (kbeg + kn + (akg << 3) + 8) <= K_real);
        return ok ? (aptr + kn) : A;
    };
    // stage B panel tile tt into ring slot tt%3: 2 contiguous 1 KB gloads/wave
    auto stageB = [&](int tt) {
        const int slot = tt % 3;
        const ushort* ps = BT2 + (((size_t)(kbeg >> 5) + tt) << 13) + ((w << 1) << 9);
        gload_lds16(ps,       &Blds[slot][(w << 1) << 9]);
        gload_lds16(ps + 512, &Blds[slot][((w << 1) + 1) << 9]);
    };
    auto writeA = [&](int buf, const f32x4& x0, const f32x4& x1) {
        union { ushort u[8]; i32x4 v4; } pk;
        pk.u[0]=f2b(x0.x); pk.u[1]=f2b(x0.y); pk.u[2]=f2b(x0.z); pk.u[3]=f2b(x0.w);
        pk.u[4]=f2b(x1.x); pk.u[5]=f2b(x1.y); pk.u[6]=f2b(x1.z); pk.u[7]=f2b(x1.w);
        *reinterpret_cast<i32x4*>(&Alds[buf][aslot << 3]) = pk.v4;
    };
    auto compute = [&](int tt) {
        const ushort* Bb = Blds[tt % 3];
        const ushort* Ab = Alds[tt & 1];
        bf16x8 bfr[4];
        #pragma unroll
        for (int nf = 0; nf < 4; ++nf)
            bfr[nf] = *reinterpret_cast<const bf16x8*>(
                &Bb[((((wn << 2) + nf) << 6) | lane) << 3]);
        #pragma unroll
        for (int mf = 0; mf < 4; ++mf) {
            const bf16x8 af = *reinterpret_cast<const bf16x8*>(
                &Ab[((((wm << 2) + mf) << 6) | lane) << 3]);
            #pragma unroll
            for (int nf = 0; nf < 4; ++nf)
                acc[mf][nf] = __builtin_amdgcn_mfma_f32_16x16x32_bf16(
                    af, bfr[nf], acc[mf][nf], 0, 0, 0);
        }
    };

    f32x4 aP0, aP1, aQ0, aQ1;
    // steady step t: stage B(t+2), load A(t+2); compute(t); end-wait drains
    // B(t+1)+A(t+1) (issued in step t-1; queue order B-then-A => vmcnt(4)).
    auto STEP = [&](int t, f32x4& c0, f32x4& c1, f32x4& n0, f32x4& n1) {
        stageB(t + 2);
        aload(apick((t + 2) << 5), n0, n1);
        compute(t);
        asm volatile("s_waitcnt vmcnt(4)" ::: "memory");
        __builtin_amdgcn_sched_barrier(0);
        writeA((t + 1) & 1, c0, c1);
        asm volatile("s_waitcnt lgkmcnt(0)" ::: "memory");
        __builtin_amdgcn_s_barrier();
    };

    // ---- prologue: queue = [B0, B1, A0, A1]; drain B0,B1,A0 ----
    stageB(0);
    stageB(1);
    aload(apick(0),  aP0, aP1);
    aload(apick(32), aQ0, aQ1);
    asm volatile("s_waitcnt vmcnt(2)" ::: "memory");
    __builtin_amdgcn_sched_barrier(0);
    writeA(0, aP0, aP1);
    asm volatile("s_waitcnt lgkmcnt(0)" ::: "memory");
    __builtin_amdgcn_s_barrier();

    // ---- main: steps t = 0 .. nt-3 (manual 2-unroll, static reg parity) ----
    int t = 0;
    for (; t + 1 < nt - 2; t += 2) {
        STEP(t,     aQ0, aQ1, aP0, aP1);
        STEP(t + 1, aP0, aP1, aQ0, aQ1);
    }
    bool lastInP = false;
    if (t < nt - 2) { STEP(t, aQ0, aQ1, aP0, aP1); lastInP = true; }

    // ---- tail: tiles nt-2 and nt-1 (everything already in flight) ----
    compute(nt - 2);
    asm volatile("s_waitcnt vmcnt(0)" ::: "memory");   // B(nt-1), A(nt-1) landed
    __builtin_amdgcn_sched_barrier(0);
    if (lastInP) writeA((nt - 1) & 1, aP0, aP1);
    else         writeA((nt - 1) & 1, aQ0, aQ1);
    asm volatile("s_waitcnt lgkmcnt(0)" ::: "memory");
    __builtin_amdgcn_s_barrier();
    compute(nt - 1);

    if constexpr (!PANEL) {
        // bf16 partial store; col = lane&15, row = (lane>>4)*4 + rr
        ushort* C = (ushort*)Cout + (size_t)sk * c_stride;
        #pragma unroll
        for (int mf = 0; mf < 4; ++mf) {
            const int rbase = row0 + (wm << 6) + mf * 16 + ((lane >> 4) << 2);
            #pragma unroll
            for (int nf = 0; nf < 4; ++nf) {
                const int col = (wn << 6) + nf * 16 + (lane & 15);
                #pragma unroll
                for (int rr = 0; rr < 4; ++rr) {
                    const int row = rbase + rr;
                    if (row < M) C[(size_t)row * HID + col] = f2b(acc[mf][nf][rr]);
                }
            }
        }
    } else {
        // bf16 panel store via LDS re-layout; block covers panels (row0>>5)+0..3
        // (rows >= M emit zeros -> pad panels written by the tail block).
        // Lp = ring slot nt%3: last read at compute(nt-3), >=1 barrier ago.
        ushort* Cp = (ushort*)Cout;
        ushort* Lp = Blds[nt % 3];
        #pragma unroll
        for (int pp = 0; pp < 4; ++pp) {
            if ((w >> 2) == (pp >> 1)) {
                #pragma unroll
                for (int mfh = 0; mfh < 2; ++mfh) {
                    const int mf = ((pp & 1) << 1) + mfh;
                    const int kb = (mfh << 4) + ((lane >> 4) << 2);  // 0..28
                    #pragma unroll
                    for (int nf = 0; nf < 4; ++nf) {
                        const int col = (wn << 6) + (nf << 4) + (lane & 15);
                        const int s = ((col >> 4) << 6) | ((kb >> 3) << 4) | (col & 15);
                        union { ushort u[4]; u32x2 v; } pk;
                        #pragma unroll
                        for (int rr = 0; rr < 4; ++rr) {
                            const int row = row0 + (pp << 5) + kb + rr;
                            pk.u[rr] = (row < M) ? f2b(acc[mf][nf][rr]) : (ushort)0;
                        }
                        *reinterpret_cast<u32x2*>(&Lp[(s << 3) + (kb & 7)]) = pk.v;
                    }
                }
            }
            __syncthreads();
            const size_t P = (size_t)((row0 >> 5) + pp);
            const ushort* sp = &Lp[tid << 4];
            ushort* gp = Cp + (P << 13) + ((size_t)tid << 4);
            *reinterpret_cast<i32x4*>(gp)     = *reinterpret_cast<const i32x4*>(sp);
            *reinterpret_cast<i32x4*>(gp + 8) = *reinterpret_cast<const i32x4*>(sp + 8);
            __syncthreads();
        }
    }
}

// ---------------------------------------------------------------------------
__global__ void k_uv(const float* __restrict__ W2, const float* __restrict__ W3,
                     float* __restrict__ c)
{
    const int j = blockIdx.x * blockDim.x + threadIdx.x;
    if (j >= 2 * HID) return;
    float s = 0.f;
    for (int m = 0; m < HID; ++m)
        s = fmaf(W2[(size_t)j * HID + m], W3[m], s);
    c[j] = s;
}

// ---------------------------------------------------------------------------
// Reduce SKA bf16 partials -> z (f32); write bf16 z table; a,b scalars
__global__ __launch_bounds__(256) void k_node(
    const ushort* __restrict__ Cpart, const float* __restrict__ c,
    ushort* __restrict__ zb, float* __restrict__ av, float* __restrict__ bv)
{
    const int node = (int)((blockIdx.x * blockDim.x + threadIdx.x) >> 6);
    const int lane = threadIdx.x & 63;
    if (node >= NN) return;

    const ushort* p0 = Cpart + (size_t)node * HID + (lane << 2);
    f32x4 s = {0.f, 0.f, 0.f, 0.f};
    #pragma unroll
    for (int p = 0; p < SKA; ++p) {
        union { u32x2 v; ushort u[4]; } raw;
        raw.v = *reinterpret_cast<const u32x2*>(p0 + (size_t)p * NN * HID);
        s.x += b2f(raw.u[0]); s.y += b2f(raw.u[1]);
        s.z += b2f(raw.u[2]); s.w += b2f(raw.u[3]);
    }

    const f32x4 u4 = *reinterpret_cast<const f32x4*>(&c[(lane << 2)]);
    const f32x4 v4 = *reinterpret_cast<const f32x4*>(&c[HID + (lane << 2)]);

    union { ushort u[4]; u32x2 v; } pz;
    pz.u[0] = f2b(s.x); pz.u[1] = f2b(s.y);
    pz.u[2] = f2b(s.z); pz.u[3] = f2b(s.w);
    *reinterpret_cast<u32x2*>(&zb[(size_t)node * HID + (lane << 2)]) = pz.v;

    const float r0 = fmaxf(s.x, 0.f), r1 = fmaxf(s.y, 0.f);
    const float r2 = fmaxf(s.z, 0.f), r3 = fmaxf(s.w, 0.f);
    float pa = r0 * u4.x + r1 * u4.y + r2 * u4.z + r3 * u4.w;
    float pb = r0 * v4.x + r1 * v4.y + r2 * v4.z + r3 * v4.w;

    #pragma unroll
    for (int off = 32; off; off >>= 1) {
        pa += __shfl_down(pa, off);
        pb += __shfl_down(pb, off);
    }
    if (lane == 0) { av[node] = pa; bv[node] = pb; }
}

// ---------------------------------------------------------------------------
// 4 edges per wave (16 lanes each): out = sigmoid(a[i]+b[j]+sum z_i z_j w3b)
__global__ __launch_bounds__(256) void k_edge(
    const int* __restrict__ e1, const int* __restrict__ e2,
    const ushort* __restrict__ zb, const float* __restrict__ av,
    const float* __restrict__ bv, const float* __restrict__ W3,
    float* __restrict__ out)
{
    const long long wid = (((long long)blockIdx.x * blockDim.x) + threadIdx.x) >> 6;
    const int lane = threadIdx.x & 63;
    const int s16  = lane & 15;
    const long long e = 4LL * wid + (lane >> 4);
    if (e >= 2LL * NE) return;

    // per-lane w3b slice (16 f32, held in VGPRs)
    const float* w3p = W3 + HID + (s16 << 4);
    f32x4 wv[4];
    #pragma unroll
    for (int i = 0; i < 4; ++i)
        wv[i] = *reinterpret_cast<const f32x4*>(w3p + (i << 2));

    const int* ep = (e < NE) ? &e1[2 * (int)e] : &e2[2 * ((int)e - NE)];
    const int i = ep[0];
    const int j = ep[1];

    const ushort* zi = &zb[(size_t)i * HID + (s16 << 4)];
    const ushort* zj = &zb[(size_t)j * HID + (s16 << 4)];
    const bf16x8 zi0 = *reinterpret_cast<const bf16x8*>(zi);
    const bf16x8 zi1 = *reinterpret_cast<const bf16x8*>(zi + 8);
    const bf16x8 zj0 = *reinterpret_cast<const bf16x8*>(zj);
    const bf16x8 zj1 = *reinterpret_cast<const bf16x8*>(zj + 8);

    float p = 0.f;
    #pragma unroll
    for (int tt = 0; tt < 8; ++tt)
        p = fmaf(b2f((ushort)zi0[tt]) * b2f((ushort)zj0[tt]), wv[tt >> 2][tt & 3], p);
    #pragma unroll
    for (int tt = 0; tt < 8; ++tt)
        p = fmaf(b2f((ushort)zi1[tt]) * b2f((ushort)zj1[tt]), wv[2 + (tt >> 2)][tt & 3], p);

    #pragma unroll
    for (int m = 8; m; m >>= 1)
        p += __shfl_xor(p, m);

    if (s16 == 0) {
        const float logit = av[i] + bv[j] + p;
        out[e] = 1.f / (1.f + expf(-logit));
    }
}

// ---------------------------------------------------------------------------
extern "C" void kernel_launch(void* const* d_in, const int* in_sizes, int n_in,
                              void* d_out, int out_size, void* d_ws, size_t ws_size,
                              hipStream_t stream)
{
    const float* X   = (const float*)d_in[0];
    const float* adj = (const float*)d_in[1];
    const int*   e1  = (const int*)d_in[2];
    const int*   e2  = (const int*)d_in[3];
    const float* W   = (const float*)d_in[4];
    const float* W2  = (const float*)d_in[5];
    const float* W3  = (const float*)d_in[6];
    float* out = (float*)d_out;

    float*  ws    = (float*)d_ws;
    float*  a     = ws;                                  // NN
    float*  b     = a + NN;                              // NN
    float*  c     = b + NN;                              // 512
    ushort* Wt2   = (ushort*)(c + 512);                  // 16 panels * 8192
    ushort* XWt2  = Wt2  + (size_t)16 * 8192;            // 320 panels * 8192
    ushort* zb    = XWt2 + (size_t)320 * 8192;           // NN*HID
    ushort* Cpart = zb + (size_t)NN * HID;               // SKA*NN*HID bf16

    const dim3 blk(256);

    // W -> tiled bf16 panels (K=512 -> 16 panels)
    cvt_tiled<<<dim3(16), blk, 0, stream>>>(W, Wt2, IND);

    // XW panels = X @ W, fused panel epilogue; grid 80 also writes pad panels
    gemm_bt<true><<<dim3(80, 1), dim3(512), 0, stream>>>(
        X, Wt2, XWt2, NN, IND, IND, IND, 0);

    // Cpart = adj @ XW  (split-K = 8, direct bf16 store)
    gemm_bt<false><<<dim3(79, SKA), dim3(512), 0, stream>>>(
        adj, XWt2, Cpart, NN, NN, NN, KCHA, (size_t)NN * HID);

    // c = [u; v]
    k_uv<<<dim3(2), blk, 0, stream>>>(W2, W3, c);

    // reduce bf16 partials + z table + a,b
    k_node<<<dim3((NN * 64) / 256), blk, 0, stream>>>(Cpart, c, zb, a, b);

    // per-edge output (4 edges / wave)
    k_edge<<<dim3((2 * NE * 16) / 256), blk, 0, stream>>>(e1, e2, zb, a, b, W3, out);
}

// Round 14
// 240.848 us; speedup vs baseline: 1.5252x; 1.0868x over previous
//
#include <hip/hip_runtime.h>
#include <hip/hip_bf16.h>
#include <math.h>

#define NN   10000
#define IND  512
#define HID  256
#define NE   400000
#define KPAD 10240   // adj GEMM K padded (320 panels of 32)
#define SKA  4       // adj split-K: k_chunk 2560, nt 80
#define KCHA 2560
#define BM   128
#define ZSCALE  1024.0f          // z stored as fp8(z * ZSCALE)
#define ZSCINV  (1.0f / (1048576.0f))   // 1 / ZSCALE^2

typedef __attribute__((ext_vector_type(4))) float  f32x4;
typedef __attribute__((ext_vector_type(2))) float  f32x2;
typedef __attribute__((ext_vector_type(4))) int    i32x4;
typedef __attribute__((ext_vector_type(2))) uint   u32x2;
typedef __attribute__((ext_vector_type(8))) short  bf16x8;

static __device__ inline ushort f2b(float f) {
    union { __hip_bfloat16 b; ushort u; } c;
    c.b = __float2bfloat16(f);
    return c.u;
}
static __device__ inline float b2f(ushort u) {
    union { uint t; float f; } c;
    c.t = (uint)u << 16;
    return c.f;
}
static __device__ inline void gload_lds16(const void* g, void* l) {
    __builtin_amdgcn_global_load_lds(
        (const __attribute__((address_space(1))) unsigned int*)g,
        (__attribute__((address_space(3))) unsigned int*)l, 16, 0, 0);
}
// pinned-order A prefetch: exactly 2 vmem loads (vmcnt accounting)
static __device__ inline void aload(const float* p, f32x4& a, f32x4& b) {
    asm volatile("global_load_dwordx4 %0, %2, off\n\t"
                 "global_load_dwordx4 %1, %2, off offset:16"
                 : "=&v"(a), "=&v"(b) : "v"(p) : "memory");
}

// ---------------------------------------------------------------------------
// W -> K-step panels (16 KB each), panel linear order == GEMM LDS frag order:
//   slot s (16 B): g = s>>6, l = s&63 -> B[col = g*16 + (l&15)][k8 = l>>4]
__global__ __launch_bounds__(256) void cvt_tiled(
    const float* __restrict__ src, ushort* __restrict__ dst, int R)
{
    __shared__ float t[32][256];
    const int p   = blockIdx.x;
    const int tid = threadIdx.x;
    const int r0  = p << 5;

    #pragma unroll
    for (int j = 0; j < 8; ++j) {
        const int f   = (j << 8) + tid;
        const int row = f >> 6;
        const int c4  = (f & 63) << 2;
        f32x4 v = {0.f, 0.f, 0.f, 0.f};
        if (r0 + row < R)
            v = *reinterpret_cast<const f32x4*>(&src[(size_t)(r0 + row) * 256 + c4]);
        *reinterpret_cast<f32x4*>(&t[row][c4]) = v;
    }
    __syncthreads();

    #pragma unroll
    for (int qq = 0; qq < 4; ++qq) {
        const int s   = (qq << 8) + tid;
        const int g   = s >> 6, l = s & 63;
        const int col = (g << 4) + (l & 15);
        const int k8  = (l >> 4) << 3;
        union { ushort u[8]; i32x4 v4; } pk;
        #pragma unroll
        for (int i = 0; i < 8; ++i) pk.u[i] = f2b(t[k8 + i][col]);
        *reinterpret_cast<i32x4*>(&dst[((size_t)p << 13) + ((size_t)s << 3)]) = pk.v4;
    }
}

// ---------------------------------------------------------------------------
// PANEL=false: Cpart[sk][M,256] bf16 = A[M, chunk] @ B(chunk), direct store.
// PANEL=true : Cout = bf16 K-step panels of (A @ B) (fused cvt_tiled), sk==0;
//              grid covers ceil(KPAD/128) row tiles so pad panels emit zeros.
// A f32 (cvt bf16 on the fly, reg->LDS dbuf), B pre-tiled bf16 panels staged
// 2 steps ahead into a ring-3 LDS buffer via contiguous 1 KB global_load_lds.
// 128x256 block, 8 waves (2x4), wave tile 64x64, BK=32. Per step exactly one
// "s_waitcnt vmcnt(4)" (drains B(t+1)+A(t+1), both issued a full step earlier)
// + lgkmcnt(0) + barrier. No mid-loop drain; tail drains vmcnt(0).
template<bool PANEL>
__global__ __launch_bounds__(512, 4) void gemm_bt(
    const float* __restrict__ A, const ushort* __restrict__ BT2,
    void* __restrict__ Cout, int M, int K_real, int lda, int k_chunk,
    size_t c_stride)
{
    __shared__ ushort Alds[2][4096];   // 16 KB (A dbuf)
    __shared__ ushort Blds[3][8192];   // 48 KB (B ring-3)

    const int tid  = threadIdx.x;      // 0..511
    const int lane = tid & 63;
    const int w    = tid >> 6;         // wave 0..7
    const int wm   = w >> 2;           // row half
    const int wn   = w & 3;            // col quadrant

    // bijective XCD-chunk swizzle; row fastest, sk-major
    const int gx  = gridDim.x;
    const int nwg = gx * gridDim.y;
    const int lin = blockIdx.y * gx + blockIdx.x;
    const int q = nwg >> 3, r = nwg & 7;
    const int xc = lin & 7, o = lin >> 3;
    const int work = (xc < r ? xc * (q + 1) : r * (q + 1) + (xc - r) * q) + o;
    const int row0 = (work % gx) * BM;
    const int sk   = work / gx;
    const int kbeg = sk * k_chunk;

    // A staging: thread t -> (row t>>2, kgroup t&3); LDS slot = inverse frag map
    const int arow = tid >> 2;
    const int akg  = tid & 3;
    const int grow = row0 + arow;
    const bool aok = grow < M;
    const bool lastrow = (grow == M - 1);
    const float* aptr = A + (size_t)grow * lda + kbeg + (akg << 3);
    const int aslot = ((arow >> 4) << 6) | (akg << 4) | (arow & 15);

    const int nt = k_chunk >> 5;       // 80 or 16 (even, >= 4)

    f32x4 acc[4][4];
    #pragma unroll
    for (int i = 0; i < 4; ++i)
        #pragma unroll
        for (int j = 0; j < 4; ++j)
            acc[i][j] = (f32x4){0.f, 0.f, 0.f, 0.f};

    auto apick = [&](int kn) -> const float* {
        const bool ok = aok && (kn < k_chunk) &&
                        (!lastrow || (kbeg + kn + (akg << 3) + 8) <= K_real);
        return ok ? (aptr + kn) : A;
    };
    // stage B panel tile tt into ring slot tt%3: 2 contiguous 1 KB gloads/wave
    auto stageB = [&](int tt) {
        const int slot = tt % 3;
        const ushort* ps = BT2 + (((size_t)(kbeg >> 5) + tt) << 13) + ((w << 1) << 9);
        gload_lds16(ps,       &Blds[slot][(w << 1) << 9]);
        gload_lds16(ps + 512, &Blds[slot][((w << 1) + 1) << 9]);
    };
    auto writeA = [&](int buf, const f32x4& x0, const f32x4& x1) {
        union { ushort u[8]; i32x4 v4; } pk;
        pk.u[0]=f2b(x0.x); pk.u[1]=f2b(x0.y); pk.u[2]=f2b(x0.z); pk.u[3]=f2b(x0.w);
        pk.u[4]=f2b(x1.x); pk.u[5]=f2b(x1.y); pk.u[6]=f2b(x1.z); pk.u[7]=f2b(x1.w);
        *reinterpret_cast<i32x4*>(&Alds[buf][aslot << 3]) = pk.v4;
    };
    auto compute = [&](int tt) {
        const ushort* Bb = Blds[tt % 3];
        const ushort* Ab = Alds[tt & 1];
        bf16x8 bfr[4];
        #pragma unroll
        for (int nf = 0; nf < 4; ++nf)
            bfr[nf] = *reinterpret_cast<const bf16x8*>(
                &Bb[((((wn << 2) + nf) << 6) | lane) << 3]);
        #pragma unroll
        for (int mf = 0; mf < 4; ++mf) {
            const bf16x8 af = *reinterpret_cast<const bf16x8*>(
                &Ab[((((wm << 2) + mf) << 6) | lane) << 3]);
            #pragma unroll
            for (int nf = 0; nf < 4; ++nf)
                acc[mf][nf] = __builtin_amdgcn_mfma_f32_16x16x32_bf16(
                    af, bfr[nf], acc[mf][nf], 0, 0, 0);
        }
    };

    f32x4 aP0, aP1, aQ0, aQ1;
    // steady step t: stage B(t+2), load A(t+2); compute(t); end-wait drains
    // B(t+1)+A(t+1) (issued in step t-1; queue order B-then-A => vmcnt(4)).
    auto STEP = [&](int t, f32x4& c0, f32x4& c1, f32x4& n0, f32x4& n1) {
        stageB(t + 2);
        aload(apick((t + 2) << 5), n0, n1);
        compute(t);
        asm volatile("s_waitcnt vmcnt(4)" ::: "memory");
        __builtin_amdgcn_sched_barrier(0);
        writeA((t + 1) & 1, c0, c1);
        asm volatile("s_waitcnt lgkmcnt(0)" ::: "memory");
        __builtin_amdgcn_s_barrier();
    };

    // ---- prologue: queue = [B0, B1, A0, A1]; drain B0,B1,A0 ----
    stageB(0);
    stageB(1);
    aload(apick(0),  aP0, aP1);
    aload(apick(32), aQ0, aQ1);
    asm volatile("s_waitcnt vmcnt(2)" ::: "memory");
    __builtin_amdgcn_sched_barrier(0);
    writeA(0, aP0, aP1);
    asm volatile("s_waitcnt lgkmcnt(0)" ::: "memory");
    __builtin_amdgcn_s_barrier();

    // ---- main: steps t = 0 .. nt-3 (manual 2-unroll, static reg parity) ----
    int t = 0;
    for (; t + 1 < nt - 2; t += 2) {
        STEP(t,     aQ0, aQ1, aP0, aP1);
        STEP(t + 1, aP0, aP1, aQ0, aQ1);
    }
    bool lastInP = false;
    if (t < nt - 2) { STEP(t, aQ0, aQ1, aP0, aP1); lastInP = true; }

    // ---- tail: tiles nt-2 and nt-1 (everything already in flight) ----
    compute(nt - 2);
    asm volatile("s_waitcnt vmcnt(0)" ::: "memory");   // B(nt-1), A(nt-1) landed
    __builtin_amdgcn_sched_barrier(0);
    if (lastInP) writeA((nt - 1) & 1, aP0, aP1);
    else         writeA((nt - 1) & 1, aQ0, aQ1);
    asm volatile("s_waitcnt lgkmcnt(0)" ::: "memory");
    __builtin_amdgcn_s_barrier();
    compute(nt - 1);

    if constexpr (!PANEL) {
        // bf16 partial store; col = lane&15, row = (lane>>4)*4 + rr
        ushort* C = (ushort*)Cout + (size_t)sk * c_stride;
        #pragma unroll
        for (int mf = 0; mf < 4; ++mf) {
            const int rbase = row0 + (wm << 6) + mf * 16 + ((lane >> 4) << 2);
            #pragma unroll
            for (int nf = 0; nf < 4; ++nf) {
                const int col = (wn << 6) + nf * 16 + (lane & 15);
                #pragma unroll
                for (int rr = 0; rr < 4; ++rr) {
                    const int row = rbase + rr;
                    if (row < M) C[(size_t)row * HID + col] = f2b(acc[mf][nf][rr]);
                }
            }
        }
    } else {
        // bf16 panel store via LDS re-layout; block covers panels (row0>>5)+0..3
        // (rows >= M emit zeros -> pad panels written by the tail block).
        // Lp = ring slot nt%3: last read at compute(nt-3), >=1 barrier ago.
        ushort* Cp = (ushort*)Cout;
        ushort* Lp = Blds[nt % 3];
        #pragma unroll
        for (int pp = 0; pp < 4; ++pp) {
            if ((w >> 2) == (pp >> 1)) {
                #pragma unroll
                for (int mfh = 0; mfh < 2; ++mfh) {
                    const int mf = ((pp & 1) << 1) + mfh;
                    const int kb = (mfh << 4) + ((lane >> 4) << 2);  // 0..28
                    #pragma unroll
                    for (int nf = 0; nf < 4; ++nf) {
                        const int col = (wn << 6) + (nf << 4) + (lane & 15);
                        const int s = ((col >> 4) << 6) | ((kb >> 3) << 4) | (col & 15);
                        union { ushort u[4]; u32x2 v; } pk;
                        #pragma unroll
                        for (int rr = 0; rr < 4; ++rr) {
                            const int row = row0 + (pp << 5) + kb + rr;
                            pk.u[rr] = (row < M) ? f2b(acc[mf][nf][rr]) : (ushort)0;
                        }
                        *reinterpret_cast<u32x2*>(&Lp[(s << 3) + (kb & 7)]) = pk.v;
                    }
                }
            }
            __syncthreads();
            const size_t P = (size_t)((row0 >> 5) + pp);
            const ushort* sp = &Lp[tid << 4];
            ushort* gp = Cp + (P << 13) + ((size_t)tid << 4);
            *reinterpret_cast<i32x4*>(gp)     = *reinterpret_cast<const i32x4*>(sp);
            *reinterpret_cast<i32x4*>(gp + 8) = *reinterpret_cast<const i32x4*>(sp + 8);
            __syncthreads();
        }
    }
}

// ---------------------------------------------------------------------------
__global__ void k_uv(const float* __restrict__ W2, const float* __restrict__ W3,
                     float* __restrict__ c)
{
    const int j = blockIdx.x * blockDim.x + threadIdx.x;
    if (j >= 2 * HID) return;
    float s = 0.f;
    for (int m = 0; m < HID; ++m)
        s = fmaf(W2[(size_t)j * HID + m], W3[m], s);
    c[j] = s;
}

// ---------------------------------------------------------------------------
// Reduce SKA bf16 partials -> z (f32); write fp8 z table (scaled); a,b scalars
__global__ __launch_bounds__(256) void k_node(
    const ushort* __restrict__ Cpart, const float* __restrict__ c,
    uint* __restrict__ zb8, float* __restrict__ av, float* __restrict__ bv)
{
    const int node = (int)((blockIdx.x * blockDim.x + threadIdx.x) >> 6);
    const int lane = threadIdx.x & 63;
    if (node >= NN) return;

    const ushort* p0 = Cpart + (size_t)node * HID + (lane << 2);
    f32x4 s = {0.f, 0.f, 0.f, 0.f};
    #pragma unroll
    for (int p = 0; p < SKA; ++p) {
        union { u32x2 v; ushort u[4]; } raw;
        raw.v = *reinterpret_cast<const u32x2*>(p0 + (size_t)p * NN * HID);
        s.x += b2f(raw.u[0]); s.y += b2f(raw.u[1]);
        s.z += b2f(raw.u[2]); s.w += b2f(raw.u[3]);
    }

    const f32x4 u4 = *reinterpret_cast<const f32x4*>(&c[(lane << 2)]);
    const f32x4 v4 = *reinterpret_cast<const f32x4*>(&c[HID + (lane << 2)]);

    // fp8 e4m3 pack of z * ZSCALE (4 elems per lane -> one u32)
    int pk8 = __builtin_amdgcn_cvt_pk_fp8_f32(s.x * ZSCALE, s.y * ZSCALE, 0, false);
    pk8     = __builtin_amdgcn_cvt_pk_fp8_f32(s.z * ZSCALE, s.w * ZSCALE, pk8, true);
    zb8[node * 64 + lane] = (uint)pk8;

    const float r0 = fmaxf(s.x, 0.f), r1 = fmaxf(s.y, 0.f);
    const float r2 = fmaxf(s.z, 0.f), r3 = fmaxf(s.w, 0.f);
    float pa = r0 * u4.x + r1 * u4.y + r2 * u4.z + r3 * u4.w;
    float pb = r0 * v4.x + r1 * v4.y + r2 * v4.z + r3 * v4.w;

    #pragma unroll
    for (int off = 32; off; off >>= 1) {
        pa += __shfl_down(pa, off);
        pb += __shfl_down(pb, off);
    }
    if (lane == 0) { av[node] = pa; bv[node] = pb; }
}

// ---------------------------------------------------------------------------
// 4 edges per wave (16 lanes each); fp8 z table (256 B/row, L2-resident):
// out = sigmoid(a[i] + b[j] + sum z_i z_j w3b / ZSCALE^2)
__global__ __launch_bounds__(256) void k_edge(
    const int* __restrict__ e1, const int* __restrict__ e2,
    const uint* __restrict__ zb8, const float* __restrict__ av,
    const float* __restrict__ bv, const float* __restrict__ W3,
    float* __restrict__ out)
{
    const long long wid = (((long long)blockIdx.x * blockDim.x) + threadIdx.x) >> 6;
    const int lane = threadIdx.x & 63;
    const int s16  = lane & 15;
    const long long e = 4LL * wid + (lane >> 4);
    if (e >= 2LL * NE) return;

    // per-lane w3b slice (16 f32), pre-scaled by 1/ZSCALE^2
    const float* w3p = W3 + HID + (s16 << 4);
    f32x4 wv[4];
    #pragma unroll
    for (int i = 0; i < 4; ++i) {
        f32x4 t = *reinterpret_cast<const f32x4*>(w3p + (i << 2));
        wv[i] = t * ZSCINV;
    }

    const int* ep = (e < NE) ? &e1[2 * (int)e] : &e2[2 * ((int)e - NE)];
    const int i = ep[0];
    const int j = ep[1];

    // 16 fp8 elems per lane per row = one dwordx4
    const i32x4 vi = *reinterpret_cast<const i32x4*>(&zb8[i * 64 + (s16 << 2)]);
    const i32x4 vj = *reinterpret_cast<const i32x4*>(&zb8[j * 64 + (s16 << 2)]);

    float p = 0.f;
    #pragma unroll
    for (int qq = 0; qq < 4; ++qq) {
        const f32x2 il = __builtin_amdgcn_cvt_pk_f32_fp8(vi[qq], false);
        const f32x2 ih = __builtin_amdgcn_cvt_pk_f32_fp8(vi[qq], true);
        const f32x2 jl = __builtin_amdgcn_cvt_pk_f32_fp8(vj[qq], false);
        const f32x2 jh = __builtin_amdgcn_cvt_pk_f32_fp8(vj[qq], true);
        p = fmaf(il.x * jl.x, wv[qq].x, p);
        p = fmaf(il.y * jl.y, wv[qq].y, p);
        p = fmaf(ih.x * jh.x, wv[qq].z, p);
        p = fmaf(ih.y * jh.y, wv[qq].w, p);
    }

    #pragma unroll
    for (int m = 8; m; m >>= 1)
        p += __shfl_xor(p, m);

    if (s16 == 0) {
        const float logit = av[i] + bv[j] + p;
        out[e] = 1.f / (1.f + expf(-logit));
    }
}

// ---------------------------------------------------------------------------
extern "C" void kernel_launch(void* const* d_in, const int* in_sizes, int n_in,
                              void* d_out, int out_size, void* d_ws, size_t ws_size,
                              hipStream_t stream)
{
    const float* X   = (const float*)d_in[0];
    const float* adj = (const float*)d_in[1];
    const int*   e1  = (const int*)d_in[2];
    const int*   e2  = (const int*)d_in[3];
    const float* W   = (const float*)d_in[4];
    const float* W2  = (const float*)d_in[5];
    const float* W3  = (const float*)d_in[6];
    float* out = (float*)d_out;

    float*  ws    = (float*)d_ws;
    float*  a     = ws;                                  // NN
    float*  b     = a + NN;                              // NN
    float*  c     = b + NN;                              // 512
    ushort* Wt2   = (ushort*)(c + 512);                  // 16 panels * 8192
    ushort* XWt2  = Wt2  + (size_t)16 * 8192;            // 320 panels * 8192
    uint*   zb8   = (uint*)(XWt2 + (size_t)320 * 8192);  // NN*64 u32 (fp8 z)
    ushort* Cpart = (ushort*)(zb8 + (size_t)NN * 64);    // SKA*NN*HID bf16

    const dim3 blk(256);

    // W -> tiled bf16 panels (K=512 -> 16 panels)
    cvt_tiled<<<dim3(16), blk, 0, stream>>>(W, Wt2, IND);

    // XW panels = X @ W, fused panel epilogue; grid 80 also writes pad panels
    gemm_bt<true><<<dim3(80, 1), dim3(512), 0, stream>>>(
        X, Wt2, XWt2, NN, IND, IND, IND, 0);

    // Cpart = adj @ XW  (split-K = 4, direct bf16 store, all blocks resident)
    gemm_bt<false><<<dim3(79, SKA), dim3(512), 0, stream>>>(
        adj, XWt2, Cpart, NN, NN, NN, KCHA, (size_t)NN * HID);

    // c = [u; v]
    k_uv<<<dim3(2), blk, 0, stream>>>(W2, W3, c);

    // reduce bf16 partials + fp8 z table + a,b
    k_node<<<dim3((NN * 64) / 256), blk, 0, stream>>>(Cpart, c, zb8, a, b);

    // per-edge output (4 edges / wave, fp8 gathers)
    k_edge<<<dim3((2 * NE * 16) / 256), blk, 0, stream>>>(e1, e2, zb8, a, b, W3, out);
}

// Round 15
// 209.525 us; speedup vs baseline: 1.7532x; 1.1495x over previous
//
#include <hip/hip_runtime.h>
#include <hip/hip_bf16.h>
#include <math.h>

#define NN   10000
#define IND  512
#define HID  256
#define NE   400000
#define KPAD 10368   // adj GEMM K padded (324 panels of 32; 54*192)
#define SKA  6       // adj split-K: k_chunk 1728, nt 54; grid 474 (~2/CU, 93% eff)
#define KCHA 1728
#define BM   128
#define ZSCALE  1024.0f          // z stored as fp8(z * ZSCALE)
#define ZSCINV  (1.0f / (1048576.0f))   // 1 / ZSCALE^2

typedef __attribute__((ext_vector_type(4))) float  f32x4;
typedef __attribute__((ext_vector_type(2))) float  f32x2;
typedef __attribute__((ext_vector_type(4))) int    i32x4;
typedef __attribute__((ext_vector_type(2))) uint   u32x2;
typedef __attribute__((ext_vector_type(8))) short  bf16x8;

static __device__ inline ushort f2b(float f) {
    union { __hip_bfloat16 b; ushort u; } c;
    c.b = __float2bfloat16(f);
    return c.u;
}
static __device__ inline float b2f(ushort u) {
    union { uint t; float f; } c;
    c.t = (uint)u << 16;
    return c.f;
}
static __device__ inline void gload_lds16(const void* g, void* l) {
    __builtin_amdgcn_global_load_lds(
        (const __attribute__((address_space(1))) unsigned int*)g,
        (__attribute__((address_space(3))) unsigned int*)l, 16, 0, 0);
}
// pinned-order A prefetch: exactly 2 vmem loads (vmcnt accounting)
static __device__ inline void aload(const float* p, f32x4& a, f32x4& b) {
    asm volatile("global_load_dwordx4 %0, %2, off\n\t"
                 "global_load_dwordx4 %1, %2, off offset:16"
                 : "=&v"(a), "=&v"(b) : "v"(p) : "memory");
}

// ---------------------------------------------------------------------------
// W -> K-step panels (16 KB each), panel linear order == GEMM LDS frag order:
//   slot s (16 B): g = s>>6, l = s&63 -> B[col = g*16 + (l&15)][k8 = l>>4]
__global__ __launch_bounds__(256) void cvt_tiled(
    const float* __restrict__ src, ushort* __restrict__ dst, int R)
{
    __shared__ float t[32][256];
    const int p   = blockIdx.x;
    const int tid = threadIdx.x;
    const int r0  = p << 5;

    #pragma unroll
    for (int j = 0; j < 8; ++j) {
        const int f   = (j << 8) + tid;
        const int row = f >> 6;
        const int c4  = (f & 63) << 2;
        f32x4 v = {0.f, 0.f, 0.f, 0.f};
        if (r0 + row < R)
            v = *reinterpret_cast<const f32x4*>(&src[(size_t)(r0 + row) * 256 + c4]);
        *reinterpret_cast<f32x4*>(&t[row][c4]) = v;
    }
    __syncthreads();

    #pragma unroll
    for (int qq = 0; qq < 4; ++qq) {
        const int s   = (qq << 8) + tid;
        const int g   = s >> 6, l = s & 63;
        const int col = (g << 4) + (l & 15);
        const int k8  = (l >> 4) << 3;
        union { ushort u[8]; i32x4 v4; } pk;
        #pragma unroll
        for (int i = 0; i < 8; ++i) pk.u[i] = f2b(t[k8 + i][col]);
        *reinterpret_cast<i32x4*>(&dst[((size_t)p << 13) + ((size_t)s << 3)]) = pk.v4;
    }
}

// ---------------------------------------------------------------------------
// PANEL=false: Cpart[sk][M,256] bf16 = A[M, chunk] @ B(chunk), direct store.
// PANEL=true : Cout = bf16 K-step panels of (A @ B) (fused cvt_tiled), sk==0;
//              grid covers ceil(KPAD/128) row tiles so pad panels emit zeros.
// A f32 (cvt bf16 on the fly, reg->LDS dbuf), B pre-tiled bf16 panels staged
// 2 steps ahead into a ring-3 LDS buffer via contiguous 1 KB global_load_lds.
// 128x256 block, 8 waves (2x4), wave tile 64x64, BK=32. Per step exactly one
// "s_waitcnt vmcnt(4)" (drains B(t+1)+A(t+1), both issued a full step earlier)
// + lgkmcnt(0) + barrier. No mid-loop drain; tail drains vmcnt(0).
template<bool PANEL>
__global__ __launch_bounds__(512, 4) void gemm_bt(
    const float* __restrict__ A, const ushort* __restrict__ BT2,
    void* __restrict__ Cout, int M, int K_real, int lda, int k_chunk,
    size_t c_stride)
{
    __shared__ ushort Alds[2][4096];   // 16 KB (A dbuf)
    __shared__ ushort Blds[3][8192];   // 48 KB (B ring-3)

    const int tid  = threadIdx.x;      // 0..511
    const int lane = tid & 63;
    const int w    = tid >> 6;         // wave 0..7
    const int wm   = w >> 2;           // row half
    const int wn   = w & 3;            // col quadrant

    // bijective XCD-chunk swizzle; row fastest, sk-major
    const int gx  = gridDim.x;
    const int nwg = gx * gridDim.y;
    const int lin = blockIdx.y * gx + blockIdx.x;
    const int q = nwg >> 3, r = nwg & 7;
    const int xc = lin & 7, o = lin >> 3;
    const int work = (xc < r ? xc * (q + 1) : r * (q + 1) + (xc - r) * q) + o;
    const int row0 = (work % gx) * BM;
    const int sk   = work / gx;
    const int kbeg = sk * k_chunk;

    // A staging: thread t -> (row t>>2, kgroup t&3); LDS slot = inverse frag map
    const int arow = tid >> 2;
    const int akg  = tid & 3;
    const int grow = row0 + arow;
    const bool aok = grow < M;
    const bool lastrow = (grow == M - 1);
    const float* aptr = A + (size_t)grow * lda + kbeg + (akg << 3);
    const int aslot = ((arow >> 4) << 6) | (akg << 4) | (arow & 15);

    const int nt = k_chunk >> 5;       // 54 or 16 (even, >= 4)

    f32x4 acc[4][4];
    #pragma unroll
    for (int i = 0; i < 4; ++i)
        #pragma unroll
        for (int j = 0; j < 4; ++j)
            acc[i][j] = (f32x4){0.f, 0.f, 0.f, 0.f};

    auto apick = [&](int kn) -> const float* {
        const bool ok = aok && (kn < k_chunk) &&
                        (!lastrow || (kbeg + kn + (akg << 3) + 8) <= K_real);
        return ok ? (aptr + kn) : A;
    };
    // stage B panel tile tt into ring slot tt%3: 2 contiguous 1 KB gloads/wave
    auto stageB = [&](int tt) {
        const int slot = tt % 3;
        const ushort* ps = BT2 + (((size_t)(kbeg >> 5) + tt) << 13) + ((w << 1) << 9);
        gload_lds16(ps,       &Blds[slot][(w << 1) << 9]);
        gload_lds16(ps + 512, &Blds[slot][((w << 1) + 1) << 9]);
    };
    auto writeA = [&](int buf, const f32x4& x0, const f32x4& x1) {
        union { ushort u[8]; i32x4 v4; } pk;
        pk.u[0]=f2b(x0.x); pk.u[1]=f2b(x0.y); pk.u[2]=f2b(x0.z); pk.u[3]=f2b(x0.w);
        pk.u[4]=f2b(x1.x); pk.u[5]=f2b(x1.y); pk.u[6]=f2b(x1.z); pk.u[7]=f2b(x1.w);
        *reinterpret_cast<i32x4*>(&Alds[buf][aslot << 3]) = pk.v4;
    };
    auto compute = [&](int tt) {
        const ushort* Bb = Blds[tt % 3];
        const ushort* Ab = Alds[tt & 1];
        bf16x8 bfr[4];
        #pragma unroll
        for (int nf = 0; nf < 4; ++nf)
            bfr[nf] = *reinterpret_cast<const bf16x8*>(
                &Bb[((((wn << 2) + nf) << 6) | lane) << 3]);
        #pragma unroll
        for (int mf = 0; mf < 4; ++mf) {
            const bf16x8 af = *reinterpret_cast<const bf16x8*>(
                &Ab[((((wm << 2) + mf) << 6) | lane) << 3]);
            #pragma unroll
            for (int nf = 0; nf < 4; ++nf)
                acc[mf][nf] = __builtin_amdgcn_mfma_f32_16x16x32_bf16(
                    af, bfr[nf], acc[mf][nf], 0, 0, 0);
        }
    };

    f32x4 aP0, aP1, aQ0, aQ1;
    // steady step t: stage B(t+2), load A(t+2); compute(t); end-wait drains
    // B(t+1)+A(t+1) (issued in step t-1; queue order B-then-A => vmcnt(4)).
    auto STEP = [&](int t, f32x4& c0, f32x4& c1, f32x4& n0, f32x4& n1) {
        stageB(t + 2);
        aload(apick((t + 2) << 5), n0, n1);
        compute(t);
        asm volatile("s_waitcnt vmcnt(4)" ::: "memory");
        __builtin_amdgcn_sched_barrier(0);
        writeA((t + 1) & 1, c0, c1);
        asm volatile("s_waitcnt lgkmcnt(0)" ::: "memory");
        __builtin_amdgcn_s_barrier();
    };

    // ---- prologue: queue = [B0, B1, A0, A1]; drain B0,B1,A0 ----
    stageB(0);
    stageB(1);
    aload(apick(0),  aP0, aP1);
    aload(apick(32), aQ0, aQ1);
    asm volatile("s_waitcnt vmcnt(2)" ::: "memory");
    __builtin_amdgcn_sched_barrier(0);
    writeA(0, aP0, aP1);
    asm volatile("s_waitcnt lgkmcnt(0)" ::: "memory");
    __builtin_amdgcn_s_barrier();

    // ---- main: steps t = 0 .. nt-3 (manual 2-unroll, static reg parity) ----
    int t = 0;
    for (; t + 1 < nt - 2; t += 2) {
        STEP(t,     aQ0, aQ1, aP0, aP1);
        STEP(t + 1, aP0, aP1, aQ0, aQ1);
    }
    bool lastInP = false;
    if (t < nt - 2) { STEP(t, aQ0, aQ1, aP0, aP1); lastInP = true; }

    // ---- tail: tiles nt-2 and nt-1 (everything already in flight) ----
    compute(nt - 2);
    asm volatile("s_waitcnt vmcnt(0)" ::: "memory");   // B(nt-1), A(nt-1) landed
    __builtin_amdgcn_sched_barrier(0);
    if (lastInP) writeA((nt - 1) & 1, aP0, aP1);
    else         writeA((nt - 1) & 1, aQ0, aQ1);
    asm volatile("s_waitcnt lgkmcnt(0)" ::: "memory");
    __builtin_amdgcn_s_barrier();
    compute(nt - 1);

    if constexpr (!PANEL) {
        // bf16 partial store; col = lane&15, row = (lane>>4)*4 + rr
        ushort* C = (ushort*)Cout + (size_t)sk * c_stride;
        #pragma unroll
        for (int mf = 0; mf < 4; ++mf) {
            const int rbase = row0 + (wm << 6) + mf * 16 + ((lane >> 4) << 2);
            #pragma unroll
            for (int nf = 0; nf < 4; ++nf) {
                const int col = (wn << 6) + nf * 16 + (lane & 15);
                #pragma unroll
                for (int rr = 0; rr < 4; ++rr) {
                    const int row = rbase + rr;
                    if (row < M) C[(size_t)row * HID + col] = f2b(acc[mf][nf][rr]);
                }
            }
        }
    } else {
        // bf16 panel store via LDS re-layout; block covers panels (row0>>5)+0..3
        // (rows >= M emit zeros -> pad panels written by the tail blocks).
        // Lp = ring slot nt%3: last read at compute(nt-3), >=1 barrier ago.
        ushort* Cp = (ushort*)Cout;
        ushort* Lp = Blds[nt % 3];
        #pragma unroll
        for (int pp = 0; pp < 4; ++pp) {
            if ((w >> 2) == (pp >> 1)) {
                #pragma unroll
                for (int mfh = 0; mfh < 2; ++mfh) {
                    const int mf = ((pp & 1) << 1) + mfh;
                    const int kb = (mfh << 4) + ((lane >> 4) << 2);  // 0..28
                    #pragma unroll
                    for (int nf = 0; nf < 4; ++nf) {
                        const int col = (wn << 6) + (nf << 4) + (lane & 15);
                        const int s = ((col >> 4) << 6) | ((kb >> 3) << 4) | (col & 15);
                        union { ushort u[4]; u32x2 v; } pk;
                        #pragma unroll
                        for (int rr = 0; rr < 4; ++rr) {
                            const int row = row0 + (pp << 5) + kb + rr;
                            pk.u[rr] = (row < M) ? f2b(acc[mf][nf][rr]) : (ushort)0;
                        }
                        *reinterpret_cast<u32x2*>(&Lp[(s << 3) + (kb & 7)]) = pk.v;
                    }
                }
            }
            __syncthreads();
            const size_t P = (size_t)((row0 >> 5) + pp);
            const ushort* sp = &Lp[tid << 4];
            ushort* gp = Cp + (P << 13) + ((size_t)tid << 4);
            *reinterpret_cast<i32x4*>(gp)     = *reinterpret_cast<const i32x4*>(sp);
            *reinterpret_cast<i32x4*>(gp + 8) = *reinterpret_cast<const i32x4*>(sp + 8);
            __syncthreads();
        }
    }
}

// ---------------------------------------------------------------------------
// c[j] = W2[j,:] . W3[0:256]  -- one wave per j, lane-parallel + shuffle reduce
__global__ __launch_bounds__(256) void k_uv(
    const float* __restrict__ W2, const float* __restrict__ W3,
    float* __restrict__ c)
{
    const int j    = (blockIdx.x * 256 + threadIdx.x) >> 6;   // 0..511
    const int lane = threadIdx.x & 63;
    const f32x4 w2 = *reinterpret_cast<const f32x4*>(&W2[(size_t)j * HID + (lane << 2)]);
    const f32x4 w3 = *reinterpret_cast<const f32x4*>(&W3[lane << 2]);
    float s = w2.x * w3.x + w2.y * w3.y + w2.z * w3.z + w2.w * w3.w;
    #pragma unroll
    for (int m = 32; m; m >>= 1) s += __shfl_xor(s, m);
    if (lane == 0) c[j] = s;
}

// ---------------------------------------------------------------------------
// Reduce SKA bf16 partials -> z (f32); write fp8 z table (scaled); a,b scalars
__global__ __launch_bounds__(256) void k_node(
    const ushort* __restrict__ Cpart, const float* __restrict__ c,
    uint* __restrict__ zb8, float* __restrict__ av, float* __restrict__ bv)
{
    const int node = (int)((blockIdx.x * blockDim.x + threadIdx.x) >> 6);
    const int lane = threadIdx.x & 63;
    if (node >= NN) return;

    const ushort* p0 = Cpart + (size_t)node * HID + (lane << 2);
    f32x4 s = {0.f, 0.f, 0.f, 0.f};
    #pragma unroll
    for (int p = 0; p < SKA; ++p) {
        union { u32x2 v; ushort u[4]; } raw;
        raw.v = *reinterpret_cast<const u32x2*>(p0 + (size_t)p * NN * HID);
        s.x += b2f(raw.u[0]); s.y += b2f(raw.u[1]);
        s.z += b2f(raw.u[2]); s.w += b2f(raw.u[3]);
    }

    const f32x4 u4 = *reinterpret_cast<const f32x4*>(&c[(lane << 2)]);
    const f32x4 v4 = *reinterpret_cast<const f32x4*>(&c[HID + (lane << 2)]);

    // fp8 e4m3 pack of z * ZSCALE (4 elems per lane -> one u32)
    int pk8 = __builtin_amdgcn_cvt_pk_fp8_f32(s.x * ZSCALE, s.y * ZSCALE, 0, false);
    pk8     = __builtin_amdgcn_cvt_pk_fp8_f32(s.z * ZSCALE, s.w * ZSCALE, pk8, true);
    zb8[node * 64 + lane] = (uint)pk8;

    const float r0 = fmaxf(s.x, 0.f), r1 = fmaxf(s.y, 0.f);
    const float r2 = fmaxf(s.z, 0.f), r3 = fmaxf(s.w, 0.f);
    float pa = r0 * u4.x + r1 * u4.y + r2 * u4.z + r3 * u4.w;
    float pb = r0 * v4.x + r1 * v4.y + r2 * v4.z + r3 * v4.w;

    #pragma unroll
    for (int off = 32; off; off >>= 1) {
        pa += __shfl_down(pa, off);
        pb += __shfl_down(pb, off);
    }
    if (lane == 0) { av[node] = pa; bv[node] = pb; }
}

// ---------------------------------------------------------------------------
// 4 edges per wave (16 lanes each); fp8 z table (256 B/row, L2-resident):
// out = sigmoid(a[i] + b[j] + sum z_i z_j w3b / ZSCALE^2)
__global__ __launch_bounds__(256) void k_edge(
    const int* __restrict__ e1, const int* __restrict__ e2,
    const uint* __restrict__ zb8, const float* __restrict__ av,
    const float* __restrict__ bv, const float* __restrict__ W3,
    float* __restrict__ out)
{
    const long long wid = (((long long)blockIdx.x * blockDim.x) + threadIdx.x) >> 6;
    const int lane = threadIdx.x & 63;
    const int s16  = lane & 15;
    const long long e = 4LL * wid + (lane >> 4);
    if (e >= 2LL * NE) return;

    // per-lane w3b slice (16 f32), pre-scaled by 1/ZSCALE^2
    const float* w3p = W3 + HID + (s16 << 4);
    f32x4 wv[4];
    #pragma unroll
    for (int i = 0; i < 4; ++i) {
        f32x4 t = *reinterpret_cast<const f32x4*>(w3p + (i << 2));
        wv[i] = t * ZSCINV;
    }

    const int* ep = (e < NE) ? &e1[2 * (int)e] : &e2[2 * ((int)e - NE)];
    const int i = ep[0];
    const int j = ep[1];

    // 16 fp8 elems per lane per row = one dwordx4
    const i32x4 vi = *reinterpret_cast<const i32x4*>(&zb8[i * 64 + (s16 << 2)]);
    const i32x4 vj = *reinterpret_cast<const i32x4*>(&zb8[j * 64 + (s16 << 2)]);

    float p = 0.f;
    #pragma unroll
    for (int qq = 0; qq < 4; ++qq) {
        const f32x2 il = __builtin_amdgcn_cvt_pk_f32_fp8(vi[qq], false);
        const f32x2 ih = __builtin_amdgcn_cvt_pk_f32_fp8(vi[qq], true);
        const f32x2 jl = __builtin_amdgcn_cvt_pk_f32_fp8(vj[qq], false);
        const f32x2 jh = __builtin_amdgcn_cvt_pk_f32_fp8(vj[qq], true);
        p = fmaf(il.x * jl.x, wv[qq].x, p);
        p = fmaf(il.y * jl.y, wv[qq].y, p);
        p = fmaf(ih.x * jh.x, wv[qq].z, p);
        p = fmaf(ih.y * jh.y, wv[qq].w, p);
    }

    #pragma unroll
    for (int m = 8; m; m >>= 1)
        p += __shfl_xor(p, m);

    if (s16 == 0) {
        const float logit = av[i] + bv[j] + p;
        out[e] = 1.f / (1.f + expf(-logit));
    }
}

// ---------------------------------------------------------------------------
extern "C" void kernel_launch(void* const* d_in, const int* in_sizes, int n_in,
                              void* d_out, int out_size, void* d_ws, size_t ws_size,
                              hipStream_t stream)
{
    const float* X   = (const float*)d_in[0];
    const float* adj = (const float*)d_in[1];
    const int*   e1  = (const int*)d_in[2];
    const int*   e2  = (const int*)d_in[3];
    const float* W   = (const float*)d_in[4];
    const float* W2  = (const float*)d_in[5];
    const float* W3  = (const float*)d_in[6];
    float* out = (float*)d_out;

    float*  ws    = (float*)d_ws;
    float*  a     = ws;                                  // NN
    float*  b     = a + NN;                              // NN
    float*  c     = b + NN;                              // 512
    ushort* Wt2   = (ushort*)(c + 512);                  // 16 panels * 8192
    ushort* XWt2  = Wt2  + (size_t)16 * 8192;            // 324 panels * 8192
    uint*   zb8   = (uint*)(XWt2 + (size_t)324 * 8192);  // NN*64 u32 (fp8 z)
    ushort* Cpart = (ushort*)(zb8 + (size_t)NN * 64);    // SKA*NN*HID bf16

    const dim3 blk(256);

    // W -> tiled bf16 panels (K=512 -> 16 panels)
    cvt_tiled<<<dim3(16), blk, 0, stream>>>(W, Wt2, IND);

    // XW panels = X @ W, fused panel epilogue; grid 81 covers 324 panels
    // (tail blocks' masked rows write the zero pad panels)
    gemm_bt<true><<<dim3(81, 1), dim3(512), 0, stream>>>(
        X, Wt2, XWt2, NN, IND, IND, IND, 0);

    // Cpart = adj @ XW  (split-K = 6 -> 474 blocks, balanced 2 rounds/CU)
    gemm_bt<false><<<dim3(79, SKA), dim3(512), 0, stream>>>(
        adj, XWt2, Cpart, NN, NN, NN, KCHA, (size_t)NN * HID);

    // c = [u; v]  (one wave per output element)
    k_uv<<<dim3(128), blk, 0, stream>>>(W2, W3, c);

    // reduce bf16 partials + fp8 z table + a,b
    k_node<<<dim3((NN * 64) / 256), blk, 0, stream>>>(Cpart, c, zb8, a, b);

    // per-edge output (4 edges / wave, fp8 gathers)
    k_edge<<<dim3((2 * NE * 16) / 256), blk, 0, stream>>>(e1, e2, zb8, a, b, W3, out);
}

// Round 16
// 189.294 us; speedup vs baseline: 1.9406x; 1.1069x over previous
//
#include <hip/hip_runtime.h>
#include <hip/hip_bf16.h>
#include <math.h>

#define NN   10000
#define IND  512
#define HID  256
#define NE   400000
#define KPAD 10368   // adj GEMM K padded (324 panels of 32; 54*192)
#define SKA  6       // adj split-K: k_chunk 1728, nt 54; grid 474 (~2/CU, 93% eff)
#define KCHA 1728
#define BM   128
#define ZSCALE  1024.0f          // z stored as fp8(z * ZSCALE)
#define ZSCINV  (1.0f / (1048576.0f))   // 1 / ZSCALE^2

typedef __attribute__((ext_vector_type(4))) float  f32x4;
typedef __attribute__((ext_vector_type(2))) float  f32x2;
typedef __attribute__((ext_vector_type(4))) int    i32x4;
typedef __attribute__((ext_vector_type(2))) uint   u32x2;
typedef __attribute__((ext_vector_type(8))) short  bf16x8;

static __device__ inline ushort f2b(float f) {
    union { __hip_bfloat16 b; ushort u; } c;
    c.b = __float2bfloat16(f);
    return c.u;
}
static __device__ inline float b2f(ushort u) {
    union { uint t; float f; } c;
    c.t = (uint)u << 16;
    return c.f;
}
static __device__ inline void gload_lds16(const void* g, void* l) {
    __builtin_amdgcn_global_load_lds(
        (const __attribute__((address_space(1))) unsigned int*)g,
        (__attribute__((address_space(3))) unsigned int*)l, 16, 0, 0);
}
// pinned-order A prefetch: exactly 2 vmem loads (vmcnt accounting)
static __device__ inline void aload(const float* p, f32x4& a, f32x4& b) {
    asm volatile("global_load_dwordx4 %0, %2, off\n\t"
                 "global_load_dwordx4 %1, %2, off offset:16"
                 : "=&v"(a), "=&v"(b) : "v"(p) : "memory");
}

// ---------------------------------------------------------------------------
// Fused prep: blocks 0..15 convert W -> 16 bf16 K-step panels (frag order);
// blocks 16..143 compute c[j] = W2[j,:]·W3 (one wave per j).
__global__ __launch_bounds__(256) void k_prep(
    const float* __restrict__ W, ushort* __restrict__ Wt2,
    const float* __restrict__ W2, const float* __restrict__ W3,
    float* __restrict__ c)
{
    __shared__ float t[32][256];
    const int tid = threadIdx.x;

    if (blockIdx.x < 16) {
        const int p  = blockIdx.x;
        const int r0 = p << 5;
        #pragma unroll
        for (int j = 0; j < 8; ++j) {
            const int f   = (j << 8) + tid;
            const int row = f >> 6;
            const int c4  = (f & 63) << 2;
            f32x4 v = {0.f, 0.f, 0.f, 0.f};
            if (r0 + row < IND)
                v = *reinterpret_cast<const f32x4*>(&W[(size_t)(r0 + row) * 256 + c4]);
            *reinterpret_cast<f32x4*>(&t[row][c4]) = v;
        }
        __syncthreads();
        #pragma unroll
        for (int qq = 0; qq < 4; ++qq) {
            const int s   = (qq << 8) + tid;
            const int g   = s >> 6, l = s & 63;
            const int col = (g << 4) + (l & 15);
            const int k8  = (l >> 4) << 3;
            union { ushort u[8]; i32x4 v4; } pk;
            #pragma unroll
            for (int i = 0; i < 8; ++i) pk.u[i] = f2b(t[k8 + i][col]);
            *reinterpret_cast<i32x4*>(&Wt2[((size_t)p << 13) + ((size_t)s << 3)]) = pk.v4;
        }
    } else {
        const int j    = ((blockIdx.x - 16) * 256 + tid) >> 6;   // 0..511
        const int lane = tid & 63;
        const f32x4 w2 = *reinterpret_cast<const f32x4*>(&W2[(size_t)j * HID + (lane << 2)]);
        const f32x4 w3 = *reinterpret_cast<const f32x4*>(&W3[lane << 2]);
        float s = w2.x * w3.x + w2.y * w3.y + w2.z * w3.z + w2.w * w3.w;
        #pragma unroll
        for (int m = 32; m; m >>= 1) s += __shfl_xor(s, m);
        if (lane == 0) c[j] = s;
    }
}

// ---------------------------------------------------------------------------
// PANEL=false: Cpart[sk][M,256] bf16 = A[M, chunk] @ B(chunk), direct store.
// PANEL=true : Cout = bf16 K-step panels of (A @ B) (fused cvt_tiled), sk==0;
//              grid covers ceil(KPAD/128) row tiles so pad panels emit zeros.
// A f32 (cvt bf16 on the fly, reg->LDS dbuf), B pre-tiled bf16 panels staged
// 2 steps ahead into a ring-3 LDS buffer via contiguous 1 KB global_load_lds.
// 128x256 block, 8 waves (2x4), wave tile 64x64, BK=32. Per step exactly one
// "s_waitcnt vmcnt(4)" (drains B(t+1)+A(t+1), both issued a full step earlier)
// + lgkmcnt(0) + barrier. No mid-loop drain; tail drains vmcnt(0).
template<bool PANEL>
__global__ __launch_bounds__(512, 4) void gemm_bt(
    const float* __restrict__ A, const ushort* __restrict__ BT2,
    void* __restrict__ Cout, int M, int K_real, int lda, int k_chunk,
    size_t c_stride)
{
    __shared__ ushort Alds[2][4096];   // 16 KB (A dbuf)
    __shared__ ushort Blds[3][8192];   // 48 KB (B ring-3)

    const int tid  = threadIdx.x;      // 0..511
    const int lane = tid & 63;
    const int w    = tid >> 6;         // wave 0..7
    const int wm   = w >> 2;           // row half
    const int wn   = w & 3;            // col quadrant

    // bijective XCD-chunk swizzle; row fastest, sk-major
    const int gx  = gridDim.x;
    const int nwg = gx * gridDim.y;
    const int lin = blockIdx.y * gx + blockIdx.x;
    const int q = nwg >> 3, r = nwg & 7;
    const int xc = lin & 7, o = lin >> 3;
    const int work = (xc < r ? xc * (q + 1) : r * (q + 1) + (xc - r) * q) + o;
    const int row0 = (work % gx) * BM;
    const int sk   = work / gx;
    const int kbeg = sk * k_chunk;

    // A staging: thread t -> (row t>>2, kgroup t&3); LDS slot = inverse frag map
    const int arow = tid >> 2;
    const int akg  = tid & 3;
    const int grow = row0 + arow;
    const bool aok = grow < M;
    const bool lastrow = (grow == M - 1);
    const float* aptr = A + (size_t)grow * lda + kbeg + (akg << 3);
    const int aslot = ((arow >> 4) << 6) | (akg << 4) | (arow & 15);

    const int nt = k_chunk >> 5;       // 54 or 16 (even, >= 4)

    f32x4 acc[4][4];
    #pragma unroll
    for (int i = 0; i < 4; ++i)
        #pragma unroll
        for (int j = 0; j < 4; ++j)
            acc[i][j] = (f32x4){0.f, 0.f, 0.f, 0.f};

    auto apick = [&](int kn) -> const float* {
        const bool ok = aok && (kn < k_chunk) &&
                        (!lastrow || (kbeg + kn + (akg << 3) + 8) <= K_real);
        return ok ? (aptr + kn) : A;
    };
    // stage B panel tile tt into ring slot tt%3: 2 contiguous 1 KB gloads/wave
    auto stageB = [&](int tt) {
        const int slot = tt % 3;
        const ushort* ps = BT2 + (((size_t)(kbeg >> 5) + tt) << 13) + ((w << 1) << 9);
        gload_lds16(ps,       &Blds[slot][(w << 1) << 9]);
        gload_lds16(ps + 512, &Blds[slot][((w << 1) + 1) << 9]);
    };
    auto writeA = [&](int buf, const f32x4& x0, const f32x4& x1) {
        union { ushort u[8]; i32x4 v4; } pk;
        pk.u[0]=f2b(x0.x); pk.u[1]=f2b(x0.y); pk.u[2]=f2b(x0.z); pk.u[3]=f2b(x0.w);
        pk.u[4]=f2b(x1.x); pk.u[5]=f2b(x1.y); pk.u[6]=f2b(x1.z); pk.u[7]=f2b(x1.w);
        *reinterpret_cast<i32x4*>(&Alds[buf][aslot << 3]) = pk.v4;
    };
    auto compute = [&](int tt) {
        const ushort* Bb = Blds[tt % 3];
        const ushort* Ab = Alds[tt & 1];
        bf16x8 bfr[4];
        #pragma unroll
        for (int nf = 0; nf < 4; ++nf)
            bfr[nf] = *reinterpret_cast<const bf16x8*>(
                &Bb[((((wn << 2) + nf) << 6) | lane) << 3]);
        #pragma unroll
        for (int mf = 0; mf < 4; ++mf) {
            const bf16x8 af = *reinterpret_cast<const bf16x8*>(
                &Ab[((((wm << 2) + mf) << 6) | lane) << 3]);
            #pragma unroll
            for (int nf = 0; nf < 4; ++nf)
                acc[mf][nf] = __builtin_amdgcn_mfma_f32_16x16x32_bf16(
                    af, bfr[nf], acc[mf][nf], 0, 0, 0);
        }
    };

    f32x4 aP0, aP1, aQ0, aQ1;
    // steady step t: stage B(t+2), load A(t+2); compute(t); end-wait drains
    // B(t+1)+A(t+1) (issued in step t-1; queue order B-then-A => vmcnt(4)).
    auto STEP = [&](int t, f32x4& c0, f32x4& c1, f32x4& n0, f32x4& n1) {
        stageB(t + 2);
        aload(apick((t + 2) << 5), n0, n1);
        compute(t);
        asm volatile("s_waitcnt vmcnt(4)" ::: "memory");
        __builtin_amdgcn_sched_barrier(0);
        writeA((t + 1) & 1, c0, c1);
        asm volatile("s_waitcnt lgkmcnt(0)" ::: "memory");
        __builtin_amdgcn_s_barrier();
    };

    // ---- prologue: queue = [B0, B1, A0, A1]; drain B0,B1,A0 ----
    stageB(0);
    stageB(1);
    aload(apick(0),  aP0, aP1);
    aload(apick(32), aQ0, aQ1);
    asm volatile("s_waitcnt vmcnt(2)" ::: "memory");
    __builtin_amdgcn_sched_barrier(0);
    writeA(0, aP0, aP1);
    asm volatile("s_waitcnt lgkmcnt(0)" ::: "memory");
    __builtin_amdgcn_s_barrier();

    // ---- main: steps t = 0 .. nt-3 (manual 2-unroll, static reg parity) ----
    int t = 0;
    for (; t + 1 < nt - 2; t += 2) {
        STEP(t,     aQ0, aQ1, aP0, aP1);
        STEP(t + 1, aP0, aP1, aQ0, aQ1);
    }
    bool lastInP = false;
    if (t < nt - 2) { STEP(t, aQ0, aQ1, aP0, aP1); lastInP = true; }

    // ---- tail: tiles nt-2 and nt-1 (everything already in flight) ----
    compute(nt - 2);
    asm volatile("s_waitcnt vmcnt(0)" ::: "memory");   // B(nt-1), A(nt-1) landed
    __builtin_amdgcn_sched_barrier(0);
    if (lastInP) writeA((nt - 1) & 1, aP0, aP1);
    else         writeA((nt - 1) & 1, aQ0, aQ1);
    asm volatile("s_waitcnt lgkmcnt(0)" ::: "memory");
    __builtin_amdgcn_s_barrier();
    compute(nt - 1);

    if constexpr (!PANEL) {
        // bf16 partial store; col = lane&15, row = (lane>>4)*4 + rr
        ushort* C = (ushort*)Cout + (size_t)sk * c_stride;
        #pragma unroll
        for (int mf = 0; mf < 4; ++mf) {
            const int rbase = row0 + (wm << 6) + mf * 16 + ((lane >> 4) << 2);
            #pragma unroll
            for (int nf = 0; nf < 4; ++nf) {
                const int col = (wn << 6) + nf * 16 + (lane & 15);
                #pragma unroll
                for (int rr = 0; rr < 4; ++rr) {
                    const int row = rbase + rr;
                    if (row < M) C[(size_t)row * HID + col] = f2b(acc[mf][nf][rr]);
                }
            }
        }
    } else {
        // bf16 panel store via LDS re-layout; block covers panels (row0>>5)+0..3
        // (rows >= M emit zeros -> pad panels written by the tail blocks).
        // Lp = ring slot nt%3: last read at compute(nt-3), >=1 barrier ago.
        ushort* Cp = (ushort*)Cout;
        ushort* Lp = Blds[nt % 3];
        #pragma unroll
        for (int pp = 0; pp < 4; ++pp) {
            if ((w >> 2) == (pp >> 1)) {
                #pragma unroll
                for (int mfh = 0; mfh < 2; ++mfh) {
                    const int mf = ((pp & 1) << 1) + mfh;
                    const int kb = (mfh << 4) + ((lane >> 4) << 2);  // 0..28
                    #pragma unroll
                    for (int nf = 0; nf < 4; ++nf) {
                        const int col = (wn << 6) + (nf << 4) + (lane & 15);
                        const int s = ((col >> 4) << 6) | ((kb >> 3) << 4) | (col & 15);
                        union { ushort u[4]; u32x2 v; } pk;
                        #pragma unroll
                        for (int rr = 0; rr < 4; ++rr) {
                            const int row = row0 + (pp << 5) + kb + rr;
                            pk.u[rr] = (row < M) ? f2b(acc[mf][nf][rr]) : (ushort)0;
                        }
                        *reinterpret_cast<u32x2*>(&Lp[(s << 3) + (kb & 7)]) = pk.v;
                    }
                }
            }
            __syncthreads();
            const size_t P = (size_t)((row0 >> 5) + pp);
            const ushort* sp = &Lp[tid << 4];
            ushort* gp = Cp + (P << 13) + ((size_t)tid << 4);
            *reinterpret_cast<i32x4*>(gp)     = *reinterpret_cast<const i32x4*>(sp);
            *reinterpret_cast<i32x4*>(gp + 8) = *reinterpret_cast<const i32x4*>(sp + 8);
            __syncthreads();
        }
    }
}

// ---------------------------------------------------------------------------
// Reduce SKA bf16 partials -> z (f32); write fp8 z table (scaled); a,b scalars
__global__ __launch_bounds__(256) void k_node(
    const ushort* __restrict__ Cpart, const float* __restrict__ c,
    uint* __restrict__ zb8, float* __restrict__ av, float* __restrict__ bv)
{
    const int node = (int)((blockIdx.x * blockDim.x + threadIdx.x) >> 6);
    const int lane = threadIdx.x & 63;
    if (node >= NN) return;

    const ushort* p0 = Cpart + (size_t)node * HID + (lane << 2);
    f32x4 s = {0.f, 0.f, 0.f, 0.f};
    #pragma unroll
    for (int p = 0; p < SKA; ++p) {
        union { u32x2 v; ushort u[4]; } raw;
        raw.v = *reinterpret_cast<const u32x2*>(p0 + (size_t)p * NN * HID);
        s.x += b2f(raw.u[0]); s.y += b2f(raw.u[1]);
        s.z += b2f(raw.u[2]); s.w += b2f(raw.u[3]);
    }

    const f32x4 u4 = *reinterpret_cast<const f32x4*>(&c[(lane << 2)]);
    const f32x4 v4 = *reinterpret_cast<const f32x4*>(&c[HID + (lane << 2)]);

    // fp8 e4m3 pack of z * ZSCALE (4 elems per lane -> one u32)
    int pk8 = __builtin_amdgcn_cvt_pk_fp8_f32(s.x * ZSCALE, s.y * ZSCALE, 0, false);
    pk8     = __builtin_amdgcn_cvt_pk_fp8_f32(s.z * ZSCALE, s.w * ZSCALE, pk8, true);
    zb8[node * 64 + lane] = (uint)pk8;

    const float r0 = fmaxf(s.x, 0.f), r1 = fmaxf(s.y, 0.f);
    const float r2 = fmaxf(s.z, 0.f), r3 = fmaxf(s.w, 0.f);
    float pa = r0 * u4.x + r1 * u4.y + r2 * u4.z + r3 * u4.w;
    float pb = r0 * v4.x + r1 * v4.y + r2 * v4.z + r3 * v4.w;

    #pragma unroll
    for (int off = 32; off; off >>= 1) {
        pa += __shfl_down(pa, off);
        pb += __shfl_down(pb, off);
    }
    if (lane == 0) { av[node] = pa; bv[node] = pb; }
}

// ---------------------------------------------------------------------------
// 8 edges per wave: each 16-lane slot handles TWO edges (4 gathers in flight);
// fp8 z table (256 B/row, L2-resident).
// out = sigmoid(a[i] + b[j] + sum z_i z_j w3b / ZSCALE^2)
__global__ __launch_bounds__(256) void k_edge(
    const int* __restrict__ e1, const int* __restrict__ e2,
    const uint* __restrict__ zb8, const float* __restrict__ av,
    const float* __restrict__ bv, const float* __restrict__ W3,
    float* __restrict__ out)
{
    const long long wid = (((long long)blockIdx.x * blockDim.x) + threadIdx.x) >> 6;
    const int lane = threadIdx.x & 63;
    const int s16  = lane & 15;
    const long long e0 = 8LL * wid + ((lane >> 4) << 1);   // even
    if (e0 >= 2LL * NE) return;
    const long long eA = e0, eB = e0 + 1;                  // eB < 2*NE (2*NE even)

    // per-lane w3b slice (16 f32), pre-scaled by 1/ZSCALE^2 (shared by both edges)
    const float* w3p = W3 + HID + (s16 << 4);
    f32x4 wv[4];
    #pragma unroll
    for (int i = 0; i < 4; ++i) {
        f32x4 t = *reinterpret_cast<const f32x4*>(w3p + (i << 2));
        wv[i] = t * ZSCINV;
    }

    const int* epA = (eA < NE) ? &e1[2 * (int)eA] : &e2[2 * ((int)eA - NE)];
    const int* epB = (eB < NE) ? &e1[2 * (int)eB] : &e2[2 * ((int)eB - NE)];
    const int iA = epA[0], jA = epA[1];
    const int iB = epB[0], jB = epB[1];

    // 4 independent dwordx4 gathers per slot
    const i32x4 viA = *reinterpret_cast<const i32x4*>(&zb8[iA * 64 + (s16 << 2)]);
    const i32x4 vjA = *reinterpret_cast<const i32x4*>(&zb8[jA * 64 + (s16 << 2)]);
    const i32x4 viB = *reinterpret_cast<const i32x4*>(&zb8[iB * 64 + (s16 << 2)]);
    const i32x4 vjB = *reinterpret_cast<const i32x4*>(&zb8[jB * 64 + (s16 << 2)]);

    float pA = 0.f, pB = 0.f;
    #pragma unroll
    for (int qq = 0; qq < 4; ++qq) {
        const f32x2 ilA = __builtin_amdgcn_cvt_pk_f32_fp8(viA[qq], false);
        const f32x2 ihA = __builtin_amdgcn_cvt_pk_f32_fp8(viA[qq], true);
        const f32x2 jlA = __builtin_amdgcn_cvt_pk_f32_fp8(vjA[qq], false);
        const f32x2 jhA = __builtin_amdgcn_cvt_pk_f32_fp8(vjA[qq], true);
        pA = fmaf(ilA.x * jlA.x, wv[qq].x, pA);
        pA = fmaf(ilA.y * jlA.y, wv[qq].y, pA);
        pA = fmaf(ihA.x * jhA.x, wv[qq].z, pA);
        pA = fmaf(ihA.y * jhA.y, wv[qq].w, pA);
        const f32x2 ilB = __builtin_amdgcn_cvt_pk_f32_fp8(viB[qq], false);
        const f32x2 ihB = __builtin_amdgcn_cvt_pk_f32_fp8(viB[qq], true);
        const f32x2 jlB = __builtin_amdgcn_cvt_pk_f32_fp8(vjB[qq], false);
        const f32x2 jhB = __builtin_amdgcn_cvt_pk_f32_fp8(vjB[qq], true);
        pB = fmaf(ilB.x * jlB.x, wv[qq].x, pB);
        pB = fmaf(ilB.y * jlB.y, wv[qq].y, pB);
        pB = fmaf(ihB.x * jhB.x, wv[qq].z, pB);
        pB = fmaf(ihB.y * jhB.y, wv[qq].w, pB);
    }

    #pragma unroll
    for (int m = 8; m; m >>= 1) {
        pA += __shfl_xor(pA, m);
        pB += __shfl_xor(pB, m);
    }

    if (s16 == 0) {
        const float lgA = av[iA] + bv[jA] + pA;
        const float lgB = av[iB] + bv[jB] + pB;
        out[eA] = 1.f / (1.f + expf(-lgA));
        out[eB] = 1.f / (1.f + expf(-lgB));
    }
}

// ---------------------------------------------------------------------------
extern "C" void kernel_launch(void* const* d_in, const int* in_sizes, int n_in,
                              void* d_out, int out_size, void* d_ws, size_t ws_size,
                              hipStream_t stream)
{
    const float* X   = (const float*)d_in[0];
    const float* adj = (const float*)d_in[1];
    const int*   e1  = (const int*)d_in[2];
    const int*   e2  = (const int*)d_in[3];
    const float* W   = (const float*)d_in[4];
    const float* W2  = (const float*)d_in[5];
    const float* W3  = (const float*)d_in[6];
    float* out = (float*)d_out;

    float*  ws    = (float*)d_ws;
    float*  a     = ws;                                  // NN
    float*  b     = a + NN;                              // NN
    float*  c     = b + NN;                              // 512
    ushort* Wt2   = (ushort*)(c + 512);                  // 16 panels * 8192
    ushort* XWt2  = Wt2  + (size_t)16 * 8192;            // 324 panels * 8192
    uint*   zb8   = (uint*)(XWt2 + (size_t)324 * 8192);  // NN*64 u32 (fp8 z)
    ushort* Cpart = (ushort*)(zb8 + (size_t)NN * 64);    // SKA*NN*HID bf16

    const dim3 blk(256);

    // fused: W -> tiled bf16 panels (blocks 0..15) + c = [u; v] (blocks 16..143)
    k_prep<<<dim3(144), blk, 0, stream>>>(W, Wt2, W2, W3, c);

    // XW panels = X @ W, fused panel epilogue; grid 81 covers 324 panels
    gemm_bt<true><<<dim3(81, 1), dim3(512), 0, stream>>>(
        X, Wt2, XWt2, NN, IND, IND, IND, 0);

    // Cpart = adj @ XW  (split-K = 6 -> 474 blocks, balanced 2 rounds/CU)
    gemm_bt<false><<<dim3(79, SKA), dim3(512), 0, stream>>>(
        adj, XWt2, Cpart, NN, NN, NN, KCHA, (size_t)NN * HID);

    // reduce bf16 partials + fp8 z table + a,b
    k_node<<<dim3((NN * 64) / 256), blk, 0, stream>>>(Cpart, c, zb8, a, b);

    // per-edge output (8 edges / wave, paired fp8 gathers)
    k_edge<<<dim3((2 * NE * 8) / 256), blk, 0, stream>>>(e1, e2, zb8, a, b, W3, out);
}

// Round 17
// 179.782 us; speedup vs baseline: 2.0433x; 1.0529x over previous
//
#include <hip/hip_runtime.h>
#include <hip/hip_bf16.h>
#include <math.h>

#define NN   10000
#define IND  512
#define HID  256
#define NE   400000
#define KPAD 10368   // adj GEMM K padded (324 panels of 32; 54*192)
#define SKA  6       // adj split-K: k_chunk 1728, nt 54; grid 474 (all co-resident)
#define KCHA 1728
#define BM   128
#define ZSCALE  1024.0f          // z stored as fp8(z * ZSCALE)
#define ZSCINV  (1.0f / (1048576.0f))   // 1 / ZSCALE^2

typedef __attribute__((ext_vector_type(4))) float  f32x4;
typedef __attribute__((ext_vector_type(2))) float  f32x2;
typedef __attribute__((ext_vector_type(4))) int    i32x4;
typedef __attribute__((ext_vector_type(2))) uint   u32x2;
typedef __attribute__((ext_vector_type(8))) short  bf16x8;

static __device__ inline ushort f2b(float f) {
    union { __hip_bfloat16 b; ushort u; } c;
    c.b = __float2bfloat16(f);
    return c.u;
}
static __device__ inline float b2f(ushort u) {
    union { uint t; float f; } c;
    c.t = (uint)u << 16;
    return c.f;
}
static __device__ inline void gload_lds16(const void* g, void* l) {
    __builtin_amdgcn_global_load_lds(
        (const __attribute__((address_space(1))) unsigned int*)g,
        (__attribute__((address_space(3))) unsigned int*)l, 16, 0, 0);
}
// pinned-order A prefetch: exactly 2 vmem loads (vmcnt accounting)
static __device__ inline void aload(const float* p, f32x4& a, f32x4& b) {
    asm volatile("global_load_dwordx4 %0, %2, off\n\t"
                 "global_load_dwordx4 %1, %2, off offset:16"
                 : "=&v"(a), "=&v"(b) : "v"(p) : "memory");
}

// ---------------------------------------------------------------------------
// Fused prep: blocks 0..15 convert W -> 16 bf16 K-step panels (frag order);
// blocks 16..143 compute c[j] = W2[j,:]·W3 (one wave per j).
__global__ __launch_bounds__(256) void k_prep(
    const float* __restrict__ W, ushort* __restrict__ Wt2,
    const float* __restrict__ W2, const float* __restrict__ W3,
    float* __restrict__ c)
{
    __shared__ float t[32][256];
    const int tid = threadIdx.x;

    if (blockIdx.x < 16) {
        const int p  = blockIdx.x;
        const int r0 = p << 5;
        #pragma unroll
        for (int j = 0; j < 8; ++j) {
            const int f   = (j << 8) + tid;
            const int row = f >> 6;
            const int c4  = (f & 63) << 2;
            f32x4 v = {0.f, 0.f, 0.f, 0.f};
            if (r0 + row < IND)
                v = *reinterpret_cast<const f32x4*>(&W[(size_t)(r0 + row) * 256 + c4]);
            *reinterpret_cast<f32x4*>(&t[row][c4]) = v;
        }
        __syncthreads();
        #pragma unroll
        for (int qq = 0; qq < 4; ++qq) {
            const int s   = (qq << 8) + tid;
            const int g   = s >> 6, l = s & 63;
            const int col = (g << 4) + (l & 15);
            const int k8  = (l >> 4) << 3;
            union { ushort u[8]; i32x4 v4; } pk;
            #pragma unroll
            for (int i = 0; i < 8; ++i) pk.u[i] = f2b(t[k8 + i][col]);
            *reinterpret_cast<i32x4*>(&Wt2[((size_t)p << 13) + ((size_t)s << 3)]) = pk.v4;
        }
    } else {
        const int j    = ((blockIdx.x - 16) * 256 + tid) >> 6;   // 0..511
        const int lane = tid & 63;
        const f32x4 w2 = *reinterpret_cast<const f32x4*>(&W2[(size_t)j * HID + (lane << 2)]);
        const f32x4 w3 = *reinterpret_cast<const f32x4*>(&W3[lane << 2]);
        float s = w2.x * w3.x + w2.y * w3.y + w2.z * w3.z + w2.w * w3.w;
        #pragma unroll
        for (int m = 32; m; m >>= 1) s += __shfl_xor(s, m);
        if (lane == 0) c[j] = s;
    }
}

// ---------------------------------------------------------------------------
// PANEL=false: Cpart[sk][M,256] bf16 = A[M, chunk] @ B(chunk), direct store.
// PANEL=true : Cout = bf16 K-step panels of (A @ B) (fused cvt_tiled), sk==0;
//              grid covers ceil(KPAD/128) row tiles so pad panels emit zeros.
// A f32 (cvt bf16 on the fly, reg->LDS dbuf), B pre-tiled bf16 panels staged
// 2 steps ahead into a ring-3 LDS buffer via contiguous 1 KB global_load_lds.
// 128x256 block, 8 waves (2x4), wave tile 64x64, BK=32. Per step exactly one
// "s_waitcnt vmcnt(4)" (drains B(t+1)+A(t+1), both issued a full step earlier)
// + lgkmcnt(0) + barrier. No mid-loop drain; tail drains vmcnt(0).
template<bool PANEL>
__global__ __launch_bounds__(512, 4) void gemm_bt(
    const float* __restrict__ A, const ushort* __restrict__ BT2,
    void* __restrict__ Cout, int M, int K_real, int lda, int k_chunk,
    size_t c_stride)
{
    __shared__ ushort Alds[2][4096];   // 16 KB (A dbuf)
    __shared__ ushort Blds[3][8192];   // 48 KB (B ring-3)

    const int tid  = threadIdx.x;      // 0..511
    const int lane = tid & 63;
    const int w    = tid >> 6;         // wave 0..7
    const int wm   = w >> 2;           // row half
    const int wn   = w & 3;            // col quadrant

    // bijective XCD-chunk swizzle; row fastest, sk-major
    const int gx  = gridDim.x;
    const int nwg = gx * gridDim.y;
    const int lin = blockIdx.y * gx + blockIdx.x;
    const int q = nwg >> 3, r = nwg & 7;
    const int xc = lin & 7, o = lin >> 3;
    const int work = (xc < r ? xc * (q + 1) : r * (q + 1) + (xc - r) * q) + o;
    const int row0 = (work % gx) * BM;
    const int sk   = work / gx;
    const int kbeg = sk * k_chunk;

    // A staging: thread t -> (row t>>2, kgroup t&3); LDS slot = inverse frag map
    const int arow = tid >> 2;
    const int akg  = tid & 3;
    const int grow = row0 + arow;
    const bool aok = grow < M;
    const bool lastrow = (grow == M - 1);
    const float* aptr = A + (size_t)grow * lda + kbeg + (akg << 3);
    const int aslot = ((arow >> 4) << 6) | (akg << 4) | (arow & 15);

    const int nt = k_chunk >> 5;       // 54 or 16 (even, >= 4)

    f32x4 acc[4][4];
    #pragma unroll
    for (int i = 0; i < 4; ++i)
        #pragma unroll
        for (int j = 0; j < 4; ++j)
            acc[i][j] = (f32x4){0.f, 0.f, 0.f, 0.f};

    auto apick = [&](int kn) -> const float* {
        const bool ok = aok && (kn < k_chunk) &&
                        (!lastrow || (kbeg + kn + (akg << 3) + 8) <= K_real);
        return ok ? (aptr + kn) : A;
    };
    // stage B panel tile tt into ring slot tt%3: 2 contiguous 1 KB gloads/wave
    auto stageB = [&](int tt) {
        const int slot = tt % 3;
        const ushort* ps = BT2 + (((size_t)(kbeg >> 5) + tt) << 13) + ((w << 1) << 9);
        gload_lds16(ps,       &Blds[slot][(w << 1) << 9]);
        gload_lds16(ps + 512, &Blds[slot][((w << 1) + 1) << 9]);
    };
    auto writeA = [&](int buf, const f32x4& x0, const f32x4& x1) {
        union { ushort u[8]; i32x4 v4; } pk;
        pk.u[0]=f2b(x0.x); pk.u[1]=f2b(x0.y); pk.u[2]=f2b(x0.z); pk.u[3]=f2b(x0.w);
        pk.u[4]=f2b(x1.x); pk.u[5]=f2b(x1.y); pk.u[6]=f2b(x1.z); pk.u[7]=f2b(x1.w);
        *reinterpret_cast<i32x4*>(&Alds[buf][aslot << 3]) = pk.v4;
    };
    auto compute = [&](int tt) {
        const ushort* Bb = Blds[tt % 3];
        const ushort* Ab = Alds[tt & 1];
        bf16x8 bfr[4];
        #pragma unroll
        for (int nf = 0; nf < 4; ++nf)
            bfr[nf] = *reinterpret_cast<const bf16x8*>(
                &Bb[((((wn << 2) + nf) << 6) | lane) << 3]);
        #pragma unroll
        for (int mf = 0; mf < 4; ++mf) {
            const bf16x8 af = *reinterpret_cast<const bf16x8*>(
                &Ab[((((wm << 2) + mf) << 6) | lane) << 3]);
            #pragma unroll
            for (int nf = 0; nf < 4; ++nf)
                acc[mf][nf] = __builtin_amdgcn_mfma_f32_16x16x32_bf16(
                    af, bfr[nf], acc[mf][nf], 0, 0, 0);
        }
    };

    f32x4 aP0, aP1, aQ0, aQ1;
    // steady step t: stage B(t+2), load A(t+2); compute(t); end-wait drains
    // B(t+1)+A(t+1) (issued in step t-1; queue order B-then-A => vmcnt(4)).
    auto STEP = [&](int t, f32x4& c0, f32x4& c1, f32x4& n0, f32x4& n1) {
        stageB(t + 2);
        aload(apick((t + 2) << 5), n0, n1);
        compute(t);
        asm volatile("s_waitcnt vmcnt(4)" ::: "memory");
        __builtin_amdgcn_sched_barrier(0);
        writeA((t + 1) & 1, c0, c1);
        asm volatile("s_waitcnt lgkmcnt(0)" ::: "memory");
        __builtin_amdgcn_s_barrier();
    };

    // ---- prologue: queue = [B0, B1, A0, A1]; drain B0,B1,A0 ----
    stageB(0);
    stageB(1);
    aload(apick(0),  aP0, aP1);
    aload(apick(32), aQ0, aQ1);
    asm volatile("s_waitcnt vmcnt(2)" ::: "memory");
    __builtin_amdgcn_sched_barrier(0);
    writeA(0, aP0, aP1);
    asm volatile("s_waitcnt lgkmcnt(0)" ::: "memory");
    __builtin_amdgcn_s_barrier();

    // ---- main: steps t = 0 .. nt-3 (manual 2-unroll, static reg parity) ----
    int t = 0;
    for (; t + 1 < nt - 2; t += 2) {
        STEP(t,     aQ0, aQ1, aP0, aP1);
        STEP(t + 1, aP0, aP1, aQ0, aQ1);
    }
    bool lastInP = false;
    if (t < nt - 2) { STEP(t, aQ0, aQ1, aP0, aP1); lastInP = true; }

    // ---- tail: tiles nt-2 and nt-1 (everything already in flight) ----
    compute(nt - 2);
    asm volatile("s_waitcnt vmcnt(0)" ::: "memory");   // B(nt-1), A(nt-1) landed
    __builtin_amdgcn_sched_barrier(0);
    if (lastInP) writeA((nt - 1) & 1, aP0, aP1);
    else         writeA((nt - 1) & 1, aQ0, aQ1);
    asm volatile("s_waitcnt lgkmcnt(0)" ::: "memory");
    __builtin_amdgcn_s_barrier();
    compute(nt - 1);

    if constexpr (!PANEL) {
        // bf16 partial store; col = lane&15, row = (lane>>4)*4 + rr
        ushort* C = (ushort*)Cout + (size_t)sk * c_stride;
        #pragma unroll
        for (int mf = 0; mf < 4; ++mf) {
            const int rbase = row0 + (wm << 6) + mf * 16 + ((lane >> 4) << 2);
            #pragma unroll
            for (int nf = 0; nf < 4; ++nf) {
                const int col = (wn << 6) + nf * 16 + (lane & 15);
                #pragma unroll
                for (int rr = 0; rr < 4; ++rr) {
                    const int row = rbase + rr;
                    if (row < M) C[(size_t)row * HID + col] = f2b(acc[mf][nf][rr]);
                }
            }
        }
    } else {
        // bf16 panel store via LDS re-layout; block covers panels (row0>>5)+0..3
        // (rows >= M emit zeros -> pad panels written by the tail blocks).
        // Lp = ring slot nt%3: last read at compute(nt-3), >=1 barrier ago.
        ushort* Cp = (ushort*)Cout;
        ushort* Lp = Blds[nt % 3];
        #pragma unroll
        for (int pp = 0; pp < 4; ++pp) {
            if ((w >> 2) == (pp >> 1)) {
                #pragma unroll
                for (int mfh = 0; mfh < 2; ++mfh) {
                    const int mf = ((pp & 1) << 1) + mfh;
                    const int kb = (mfh << 4) + ((lane >> 4) << 2);  // 0..28
                    #pragma unroll
                    for (int nf = 0; nf < 4; ++nf) {
                        const int col = (wn << 6) + (nf << 4) + (lane & 15);
                        const int s = ((col >> 4) << 6) | ((kb >> 3) << 4) | (col & 15);
                        union { ushort u[4]; u32x2 v; } pk;
                        #pragma unroll
                        for (int rr = 0; rr < 4; ++rr) {
                            const int row = row0 + (pp << 5) + kb + rr;
                            pk.u[rr] = (row < M) ? f2b(acc[mf][nf][rr]) : (ushort)0;
                        }
                        *reinterpret_cast<u32x2*>(&Lp[(s << 3) + (kb & 7)]) = pk.v;
                    }
                }
            }
            __syncthreads();
            const size_t P = (size_t)((row0 >> 5) + pp);
            const ushort* sp = &Lp[tid << 4];
            ushort* gp = Cp + (P << 13) + ((size_t)tid << 4);
            *reinterpret_cast<i32x4*>(gp)     = *reinterpret_cast<const i32x4*>(sp);
            *reinterpret_cast<i32x4*>(gp + 8) = *reinterpret_cast<const i32x4*>(sp + 8);
            __syncthreads();
        }
    }
}

// ---------------------------------------------------------------------------
// Reduce SKA bf16 partials -> z (f32); write fp8 z table; a,b scalars.
// TWO nodes per wave: lane covers 8 cols of node n0 (lanes 0..31) or n0+1.
__global__ __launch_bounds__(256) void k_node(
    const ushort* __restrict__ Cpart, const float* __restrict__ c,
    uint* __restrict__ zb8, float* __restrict__ av, float* __restrict__ bv)
{
    const int wv   = (int)((blockIdx.x * blockDim.x + threadIdx.x) >> 6);
    const int lane = threadIdx.x & 63;
    const int n0   = wv << 1;
    if (n0 >= NN) return;
    const int node = n0 + (lane >> 5);
    const int cl   = (lane & 31) << 3;            // col base 0..248

    const ushort* p0 = Cpart + (size_t)node * HID + cl;
    float s[8] = {0.f};
    #pragma unroll
    for (int p = 0; p < SKA; ++p) {
        union { i32x4 v; ushort u[8]; } raw;
        raw.v = *reinterpret_cast<const i32x4*>(p0 + (size_t)p * NN * HID);
        #pragma unroll
        for (int k = 0; k < 8; ++k) s[k] += b2f(raw.u[k]);
    }

    const f32x4 u4a = *reinterpret_cast<const f32x4*>(&c[cl]);
    const f32x4 u4b = *reinterpret_cast<const f32x4*>(&c[cl + 4]);
    const f32x4 v4a = *reinterpret_cast<const f32x4*>(&c[HID + cl]);
    const f32x4 v4b = *reinterpret_cast<const f32x4*>(&c[HID + cl + 4]);

    // fp8 e4m3 pack of z * ZSCALE (8 elems -> two u32, layout u32 u = cols 4u)
    int pkA = __builtin_amdgcn_cvt_pk_fp8_f32(s[0] * ZSCALE, s[1] * ZSCALE, 0, false);
    pkA     = __builtin_amdgcn_cvt_pk_fp8_f32(s[2] * ZSCALE, s[3] * ZSCALE, pkA, true);
    int pkB = __builtin_amdgcn_cvt_pk_fp8_f32(s[4] * ZSCALE, s[5] * ZSCALE, 0, false);
    pkB     = __builtin_amdgcn_cvt_pk_fp8_f32(s[6] * ZSCALE, s[7] * ZSCALE, pkB, true);
    union { int p[2]; u32x2 v; } z2;
    z2.p[0] = pkA; z2.p[1] = pkB;
    *reinterpret_cast<u32x2*>(&zb8[node * 64 + ((lane & 31) << 1)]) = z2.v;

    const float r0 = fmaxf(s[0], 0.f), r1 = fmaxf(s[1], 0.f);
    const float r2 = fmaxf(s[2], 0.f), r3 = fmaxf(s[3], 0.f);
    const float r4 = fmaxf(s[4], 0.f), r5 = fmaxf(s[5], 0.f);
    const float r6 = fmaxf(s[6], 0.f), r7 = fmaxf(s[7], 0.f);
    float pa = r0 * u4a.x + r1 * u4a.y + r2 * u4a.z + r3 * u4a.w
             + r4 * u4b.x + r5 * u4b.y + r6 * u4b.z + r7 * u4b.w;
    float pb = r0 * v4a.x + r1 * v4a.y + r2 * v4a.z + r3 * v4a.w
             + r4 * v4b.x + r5 * v4b.y + r6 * v4b.z + r7 * v4b.w;

    #pragma unroll
    for (int m = 16; m; m >>= 1) {        // reduce within 32-lane half
        pa += __shfl_xor(pa, m);
        pb += __shfl_xor(pb, m);
    }
    if ((lane & 31) == 0) { av[node] = pa; bv[node] = pb; }
}

// ---------------------------------------------------------------------------
// 16 edges per wave: each 16-lane slot handles FOUR edges (8 gathers in
// flight); fp8 z table (256 B/row, L2-resident); float4 output store.
// out = sigmoid(a[i] + b[j] + sum z_i z_j w3b / ZSCALE^2)
__global__ __launch_bounds__(256) void k_edge(
    const int* __restrict__ e1, const int* __restrict__ e2,
    const uint* __restrict__ zb8, const float* __restrict__ av,
    const float* __restrict__ bv, const float* __restrict__ W3,
    float* __restrict__ out)
{
    const long long wid = (((long long)blockIdx.x * blockDim.x) + threadIdx.x) >> 6;
    const int lane = threadIdx.x & 63;
    const int s16  = lane & 15;
    const long long e0 = 16LL * wid + ((lane >> 4) << 2);   // multiple of 4
    if (e0 >= 2LL * NE) return;                              // 2*NE % 16 == 0

    // per-lane w3b slice (16 f32), pre-scaled by 1/ZSCALE^2 (shared by 4 edges)
    const float* w3p = W3 + HID + (s16 << 4);
    f32x4 wv[4];
    #pragma unroll
    for (int i = 0; i < 4; ++i) {
        f32x4 t = *reinterpret_cast<const f32x4*>(w3p + (i << 2));
        wv[i] = t * ZSCINV;
    }

    int ii[4], jj[4];
    #pragma unroll
    for (int k = 0; k < 4; ++k) {
        const long long e = e0 + k;
        const int* ep = (e < NE) ? &e1[2 * (int)e] : &e2[2 * ((int)e - NE)];
        ii[k] = ep[0];
        jj[k] = ep[1];
    }

    // 8 independent dwordx4 gathers per slot
    i32x4 vi[4], vj[4];
    #pragma unroll
    for (int k = 0; k < 4; ++k) {
        vi[k] = *reinterpret_cast<const i32x4*>(&zb8[ii[k] * 64 + (s16 << 2)]);
        vj[k] = *reinterpret_cast<const i32x4*>(&zb8[jj[k] * 64 + (s16 << 2)]);
    }

    float p[4] = {0.f, 0.f, 0.f, 0.f};
    #pragma unroll
    for (int k = 0; k < 4; ++k) {
        #pragma unroll
        for (int qq = 0; qq < 4; ++qq) {
            const f32x2 il = __builtin_amdgcn_cvt_pk_f32_fp8(vi[k][qq], false);
            const f32x2 ih = __builtin_amdgcn_cvt_pk_f32_fp8(vi[k][qq], true);
            const f32x2 jl = __builtin_amdgcn_cvt_pk_f32_fp8(vj[k][qq], false);
            const f32x2 jh = __builtin_amdgcn_cvt_pk_f32_fp8(vj[k][qq], true);
            p[k] = fmaf(il.x * jl.x, wv[qq].x, p[k]);
            p[k] = fmaf(il.y * jl.y, wv[qq].y, p[k]);
            p[k] = fmaf(ih.x * jh.x, wv[qq].z, p[k]);
            p[k] = fmaf(ih.y * jh.y, wv[qq].w, p[k]);
        }
    }

    #pragma unroll
    for (int m = 8; m; m >>= 1) {
        #pragma unroll
        for (int k = 0; k < 4; ++k) p[k] += __shfl_xor(p[k], m);
    }

    if (s16 == 0) {
        f32x4 o;
        #pragma unroll
        for (int k = 0; k < 4; ++k) {
            const float lg = av[ii[k]] + bv[jj[k]] + p[k];
            o[k] = 1.f / (1.f + expf(-lg));
        }
        *reinterpret_cast<f32x4*>(&out[e0]) = o;
    }
}

// ---------------------------------------------------------------------------
extern "C" void kernel_launch(void* const* d_in, const int* in_sizes, int n_in,
                              void* d_out, int out_size, void* d_ws, size_t ws_size,
                              hipStream_t stream)
{
    const float* X   = (const float*)d_in[0];
    const float* adj = (const float*)d_in[1];
    const int*   e1  = (const int*)d_in[2];
    const int*   e2  = (const int*)d_in[3];
    const float* W   = (const float*)d_in[4];
    const float* W2  = (const float*)d_in[5];
    const float* W3  = (const float*)d_in[6];
    float* out = (float*)d_out;

    float*  ws    = (float*)d_ws;
    float*  a     = ws;                                  // NN
    float*  b     = a + NN;                              // NN
    float*  c     = b + NN;                              // 512
    ushort* Wt2   = (ushort*)(c + 512);                  // 16 panels * 8192
    ushort* XWt2  = Wt2  + (size_t)16 * 8192;            // 324 panels * 8192
    uint*   zb8   = (uint*)(XWt2 + (size_t)324 * 8192);  // NN*64 u32 (fp8 z)
    ushort* Cpart = (ushort*)(zb8 + (size_t)NN * 64);    // SKA*NN*HID bf16

    const dim3 blk(256);

    // fused: W -> tiled bf16 panels (blocks 0..15) + c = [u; v] (blocks 16..143)
    k_prep<<<dim3(144), blk, 0, stream>>>(W, Wt2, W2, W3, c);

    // XW panels = X @ W, fused panel epilogue; grid 81 covers 324 panels
    gemm_bt<true><<<dim3(81, 1), dim3(512), 0, stream>>>(
        X, Wt2, XWt2, NN, IND, IND, IND, 0);

    // Cpart = adj @ XW  (split-K = 6 -> 474 blocks, all co-resident)
    gemm_bt<false><<<dim3(79, SKA), dim3(512), 0, stream>>>(
        adj, XWt2, Cpart, NN, NN, NN, KCHA, (size_t)NN * HID);

    // reduce bf16 partials + fp8 z table + a,b  (2 nodes / wave)
    k_node<<<dim3((NN / 2 * 64) / 256), blk, 0, stream>>>(Cpart, c, zb8, a, b);

    // per-edge output (16 edges / wave, 4 per slot, float4 stores)
    k_edge<<<dim3((2 * NE * 4) / 256), blk, 0, stream>>>(e1, e2, zb8, a, b, W3, out);
}

// Round 18
// 172.421 us; speedup vs baseline: 2.1305x; 1.0427x over previous
//
#include <hip/hip_runtime.h>
#include <hip/hip_bf16.h>
#include <math.h>

#define NN   10000
#define IND  512
#define HID  256
#define NE   400000
#define KPAD 10368   // adj GEMM K padded (324 panels of 32; 54*192)
#define SKA  6       // adj split-K: k_chunk 1728, nt 54; grid 474 (all co-resident)
#define KCHA 1728
#define BM   128
#define ZSCALE  1024.0f          // z stored as fp8(z * ZSCALE)
#define ZSCINV  (1.0f / (1048576.0f))   // 1 / ZSCALE^2

typedef __attribute__((ext_vector_type(4))) float  f32x4;
typedef __attribute__((ext_vector_type(2))) float  f32x2;
typedef __attribute__((ext_vector_type(4))) int    i32x4;
typedef __attribute__((ext_vector_type(2))) uint   u32x2;
typedef __attribute__((ext_vector_type(8))) short  bf16x8;

static __device__ inline ushort f2b(float f) {
    union { __hip_bfloat16 b; ushort u; } c;
    c.b = __float2bfloat16(f);
    return c.u;
}
static __device__ inline float b2f(ushort u) {
    union { uint t; float f; } c;
    c.t = (uint)u << 16;
    return c.f;
}
static __device__ inline void gload_lds16(const void* g, void* l) {
    __builtin_amdgcn_global_load_lds(
        (const __attribute__((address_space(1))) unsigned int*)g,
        (__attribute__((address_space(3))) unsigned int*)l, 16, 0, 0);
}
// pinned-order A prefetch: exactly 2 vmem loads (vmcnt accounting)
static __device__ inline void aload(const float* p, f32x4& a, f32x4& b) {
    asm volatile("global_load_dwordx4 %0, %2, off\n\t"
                 "global_load_dwordx4 %1, %2, off offset:16"
                 : "=&v"(a), "=&v"(b) : "v"(p) : "memory");
}

// ---------------------------------------------------------------------------
// Fused prep: blocks 0..15 convert W -> 16 bf16 K-step panels (frag order);
// blocks 16..143 compute c[j] = W2[j,:]·W3 (one wave per j).
__global__ __launch_bounds__(256) void k_prep(
    const float* __restrict__ W, ushort* __restrict__ Wt2,
    const float* __restrict__ W2, const float* __restrict__ W3,
    float* __restrict__ c)
{
    __shared__ float t[32][256];
    const int tid = threadIdx.x;

    if (blockIdx.x < 16) {
        const int p  = blockIdx.x;
        const int r0 = p << 5;
        #pragma unroll
        for (int j = 0; j < 8; ++j) {
            const int f   = (j << 8) + tid;
            const int row = f >> 6;
            const int c4  = (f & 63) << 2;
            f32x4 v = {0.f, 0.f, 0.f, 0.f};
            if (r0 + row < IND)
                v = *reinterpret_cast<const f32x4*>(&W[(size_t)(r0 + row) * 256 + c4]);
            *reinterpret_cast<f32x4*>(&t[row][c4]) = v;
        }
        __syncthreads();
        #pragma unroll
        for (int qq = 0; qq < 4; ++qq) {
            const int s   = (qq << 8) + tid;
            const int g   = s >> 6, l = s & 63;
            const int col = (g << 4) + (l & 15);
            const int k8  = (l >> 4) << 3;
            union { ushort u[8]; i32x4 v4; } pk;
            #pragma unroll
            for (int i = 0; i < 8; ++i) pk.u[i] = f2b(t[k8 + i][col]);
            *reinterpret_cast<i32x4*>(&Wt2[((size_t)p << 13) + ((size_t)s << 3)]) = pk.v4;
        }
    } else {
        const int j    = ((blockIdx.x - 16) * 256 + tid) >> 6;   // 0..511
        const int lane = tid & 63;
        const f32x4 w2 = *reinterpret_cast<const f32x4*>(&W2[(size_t)j * HID + (lane << 2)]);
        const f32x4 w3 = *reinterpret_cast<const f32x4*>(&W3[lane << 2]);
        float s = w2.x * w3.x + w2.y * w3.y + w2.z * w3.z + w2.w * w3.w;
        #pragma unroll
        for (int m = 32; m; m >>= 1) s += __shfl_xor(s, m);
        if (lane == 0) c[j] = s;
    }
}

// ---------------------------------------------------------------------------
// PANEL=false: Cpart[sk][M,256] bf16 = A[M, chunk] @ B(chunk), direct store.
// PANEL=true : Cout = bf16 K-step panels of (A @ B) (fused cvt_tiled), sk==0;
//              grid covers ceil(KPAD/128) row tiles so pad panels emit zeros.
// A f32 (cvt bf16 on the fly, reg->LDS dbuf), B pre-tiled bf16 panels staged
// 2 steps ahead into a ring-3 LDS buffer via contiguous 1 KB global_load_lds.
// 128x256 block, 8 waves (2x4), wave tile 64x64, BK=32. Per step exactly one
// "s_waitcnt vmcnt(4)" (drains B(t+1)+A(t+1), both issued a full step earlier)
// + lgkmcnt(0) + barrier. No mid-loop drain; tail drains vmcnt(0).
template<bool PANEL>
__global__ __launch_bounds__(512, 4) void gemm_bt(
    const float* __restrict__ A, const ushort* __restrict__ BT2,
    void* __restrict__ Cout, int M, int K_real, int lda, int k_chunk,
    size_t c_stride)
{
    __shared__ ushort Alds[2][4096];   // 16 KB (A dbuf)
    __shared__ ushort Blds[3][8192];   // 48 KB (B ring-3)

    const int tid  = threadIdx.x;      // 0..511
    const int lane = tid & 63;
    const int w    = tid >> 6;         // wave 0..7
    const int wm   = w >> 2;           // row half
    const int wn   = w & 3;            // col quadrant

    // bijective XCD-chunk swizzle; row fastest, sk-major
    const int gx  = gridDim.x;
    const int nwg = gx * gridDim.y;
    const int lin = blockIdx.y * gx + blockIdx.x;
    const int q = nwg >> 3, r = nwg & 7;
    const int xc = lin & 7, o = lin >> 3;
    const int work = (xc < r ? xc * (q + 1) : r * (q + 1) + (xc - r) * q) + o;
    const int row0 = (work % gx) * BM;
    const int sk   = work / gx;
    const int kbeg = sk * k_chunk;

    // A staging: thread t -> (row t>>2, kgroup t&3); LDS slot = inverse frag map
    const int arow = tid >> 2;
    const int akg  = tid & 3;
    const int grow = row0 + arow;
    const bool aok = grow < M;
    const bool lastrow = (grow == M - 1);
    const float* aptr = A + (size_t)grow * lda + kbeg + (akg << 3);
    const int aslot = ((arow >> 4) << 6) | (akg << 4) | (arow & 15);

    const int nt = k_chunk >> 5;       // 54 or 16 (even, >= 4)

    f32x4 acc[4][4];
    #pragma unroll
    for (int i = 0; i < 4; ++i)
        #pragma unroll
        for (int j = 0; j < 4; ++j)
            acc[i][j] = (f32x4){0.f, 0.f, 0.f, 0.f};

    auto apick = [&](int kn) -> const float* {
        const bool ok = aok && (kn < k_chunk) &&
                        (!lastrow || (kbeg + kn + (akg << 3) + 8) <= K_real);
        return ok ? (aptr + kn) : A;
    };
    // stage B panel tile tt into ring slot tt%3: 2 contiguous 1 KB gloads/wave
    auto stageB = [&](int tt) {
        const int slot = tt % 3;
        const ushort* ps = BT2 + (((size_t)(kbeg >> 5) + tt) << 13) + ((w << 1) << 9);
        gload_lds16(ps,       &Blds[slot][(w << 1) << 9]);
        gload_lds16(ps + 512, &Blds[slot][((w << 1) + 1) << 9]);
    };
    auto writeA = [&](int buf, const f32x4& x0, const f32x4& x1) {
        union { ushort u[8]; i32x4 v4; } pk;
        pk.u[0]=f2b(x0.x); pk.u[1]=f2b(x0.y); pk.u[2]=f2b(x0.z); pk.u[3]=f2b(x0.w);
        pk.u[4]=f2b(x1.x); pk.u[5]=f2b(x1.y); pk.u[6]=f2b(x1.z); pk.u[7]=f2b(x1.w);
        *reinterpret_cast<i32x4*>(&Alds[buf][aslot << 3]) = pk.v4;
    };
    auto compute = [&](int tt) {
        const ushort* Bb = Blds[tt % 3];
        const ushort* Ab = Alds[tt & 1];
        bf16x8 bfr[4];
        #pragma unroll
        for (int nf = 0; nf < 4; ++nf)
            bfr[nf] = *reinterpret_cast<const bf16x8*>(
                &Bb[((((wn << 2) + nf) << 6) | lane) << 3]);
        #pragma unroll
        for (int mf = 0; mf < 4; ++mf) {
            const bf16x8 af = *reinterpret_cast<const bf16x8*>(
                &Ab[((((wm << 2) + mf) << 6) | lane) << 3]);
            #pragma unroll
            for (int nf = 0; nf < 4; ++nf)
                acc[mf][nf] = __builtin_amdgcn_mfma_f32_16x16x32_bf16(
                    af, bfr[nf], acc[mf][nf], 0, 0, 0);
        }
    };

    f32x4 aP0, aP1, aQ0, aQ1;
    // steady step t: stage B(t+2), load A(t+2); compute(t); end-wait drains
    // B(t+1)+A(t+1) (issued in step t-1; queue order B-then-A => vmcnt(4)).
    auto STEP = [&](int t, f32x4& c0, f32x4& c1, f32x4& n0, f32x4& n1) {
        stageB(t + 2);
        aload(apick((t + 2) << 5), n0, n1);
        compute(t);
        asm volatile("s_waitcnt vmcnt(4)" ::: "memory");
        __builtin_amdgcn_sched_barrier(0);
        writeA((t + 1) & 1, c0, c1);
        asm volatile("s_waitcnt lgkmcnt(0)" ::: "memory");
        __builtin_amdgcn_s_barrier();
    };

    // ---- prologue: queue = [B0, B1, A0, A1]; drain B0,B1,A0 ----
    stageB(0);
    stageB(1);
    aload(apick(0),  aP0, aP1);
    aload(apick(32), aQ0, aQ1);
    asm volatile("s_waitcnt vmcnt(2)" ::: "memory");
    __builtin_amdgcn_sched_barrier(0);
    writeA(0, aP0, aP1);
    asm volatile("s_waitcnt lgkmcnt(0)" ::: "memory");
    __builtin_amdgcn_s_barrier();

    // ---- main: steps t = 0 .. nt-3 (manual 2-unroll, static reg parity) ----
    int t = 0;
    for (; t + 1 < nt - 2; t += 2) {
        STEP(t,     aQ0, aQ1, aP0, aP1);
        STEP(t + 1, aP0, aP1, aQ0, aQ1);
    }
    bool lastInP = false;
    if (t < nt - 2) { STEP(t, aQ0, aQ1, aP0, aP1); lastInP = true; }

    // ---- tail: tiles nt-2 and nt-1 (everything already in flight) ----
    compute(nt - 2);
    asm volatile("s_waitcnt vmcnt(0)" ::: "memory");   // B(nt-1), A(nt-1) landed
    __builtin_amdgcn_sched_barrier(0);
    if (lastInP) writeA((nt - 1) & 1, aP0, aP1);
    else         writeA((nt - 1) & 1, aQ0, aQ1);
    asm volatile("s_waitcnt lgkmcnt(0)" ::: "memory");
    __builtin_amdgcn_s_barrier();
    compute(nt - 1);

    if constexpr (!PANEL) {
        // bf16 partial store; col = lane&15, row = (lane>>4)*4 + rr
        ushort* C = (ushort*)Cout + (size_t)sk * c_stride;
        #pragma unroll
        for (int mf = 0; mf < 4; ++mf) {
            const int rbase = row0 + (wm << 6) + mf * 16 + ((lane >> 4) << 2);
            #pragma unroll
            for (int nf = 0; nf < 4; ++nf) {
                const int col = (wn << 6) + nf * 16 + (lane & 15);
                #pragma unroll
                for (int rr = 0; rr < 4; ++rr) {
                    const int row = rbase + rr;
                    if (row < M) C[(size_t)row * HID + col] = f2b(acc[mf][nf][rr]);
                }
            }
        }
    } else {
        // bf16 panel store via LDS re-layout; block covers panels (row0>>5)+0..3
        // (rows >= M emit zeros -> pad panels written by the tail blocks).
        // Lp = ring slot nt%3: last read at compute(nt-3), >=1 barrier ago.
        ushort* Cp = (ushort*)Cout;
        ushort* Lp = Blds[nt % 3];
        #pragma unroll
        for (int pp = 0; pp < 4; ++pp) {
            if ((w >> 2) == (pp >> 1)) {
                #pragma unroll
                for (int mfh = 0; mfh < 2; ++mfh) {
                    const int mf = ((pp & 1) << 1) + mfh;
                    const int kb = (mfh << 4) + ((lane >> 4) << 2);  // 0..28
                    #pragma unroll
                    for (int nf = 0; nf < 4; ++nf) {
                        const int col = (wn << 6) + (nf << 4) + (lane & 15);
                        const int s = ((col >> 4) << 6) | ((kb >> 3) << 4) | (col & 15);
                        union { ushort u[4]; u32x2 v; } pk;
                        #pragma unroll
                        for (int rr = 0; rr < 4; ++rr) {
                            const int row = row0 + (pp << 5) + kb + rr;
                            pk.u[rr] = (row < M) ? f2b(acc[mf][nf][rr]) : (ushort)0;
                        }
                        *reinterpret_cast<u32x2*>(&Lp[(s << 3) + (kb & 7)]) = pk.v;
                    }
                }
            }
            __syncthreads();
            const size_t P = (size_t)((row0 >> 5) + pp);
            const ushort* sp = &Lp[tid << 4];
            ushort* gp = Cp + (P << 13) + ((size_t)tid << 4);
            *reinterpret_cast<i32x4*>(gp)     = *reinterpret_cast<const i32x4*>(sp);
            *reinterpret_cast<i32x4*>(gp + 8) = *reinterpret_cast<const i32x4*>(sp + 8);
            __syncthreads();
        }
    }
}

// ---------------------------------------------------------------------------
// Reduce SKA bf16 partials -> z (f32); write fp8 z table; a,b scalars.
// TWO nodes per wave: lane covers 8 cols of node n0 (lanes 0..31) or n0+1.
__global__ __launch_bounds__(256) void k_node(
    const ushort* __restrict__ Cpart, const float* __restrict__ c,
    uint* __restrict__ zb8, float* __restrict__ av, float* __restrict__ bv)
{
    const int wv   = (int)((blockIdx.x * blockDim.x + threadIdx.x) >> 6);
    const int lane = threadIdx.x & 63;
    const int n0   = wv << 1;
    if (n0 >= NN) return;
    const int node = n0 + (lane >> 5);
    const int cl   = (lane & 31) << 3;            // col base 0..248

    const ushort* p0 = Cpart + (size_t)node * HID + cl;
    float s[8] = {0.f};
    #pragma unroll
    for (int p = 0; p < SKA; ++p) {
        union { i32x4 v; ushort u[8]; } raw;
        raw.v = *reinterpret_cast<const i32x4*>(p0 + (size_t)p * NN * HID);
        #pragma unroll
        for (int k = 0; k < 8; ++k) s[k] += b2f(raw.u[k]);
    }

    const f32x4 u4a = *reinterpret_cast<const f32x4*>(&c[cl]);
    const f32x4 u4b = *reinterpret_cast<const f32x4*>(&c[cl + 4]);
    const f32x4 v4a = *reinterpret_cast<const f32x4*>(&c[HID + cl]);
    const f32x4 v4b = *reinterpret_cast<const f32x4*>(&c[HID + cl + 4]);

    // fp8 e4m3 pack of z * ZSCALE (8 elems -> two u32, layout u32 u = cols 4u)
    int pkA = __builtin_amdgcn_cvt_pk_fp8_f32(s[0] * ZSCALE, s[1] * ZSCALE, 0, false);
    pkA     = __builtin_amdgcn_cvt_pk_fp8_f32(s[2] * ZSCALE, s[3] * ZSCALE, pkA, true);
    int pkB = __builtin_amdgcn_cvt_pk_fp8_f32(s[4] * ZSCALE, s[5] * ZSCALE, 0, false);
    pkB     = __builtin_amdgcn_cvt_pk_fp8_f32(s[6] * ZSCALE, s[7] * ZSCALE, pkB, true);
    union { int p[2]; u32x2 v; } z2;
    z2.p[0] = pkA; z2.p[1] = pkB;
    *reinterpret_cast<u32x2*>(&zb8[node * 64 + ((lane & 31) << 1)]) = z2.v;

    const float r0 = fmaxf(s[0], 0.f), r1 = fmaxf(s[1], 0.f);
    const float r2 = fmaxf(s[2], 0.f), r3 = fmaxf(s[3], 0.f);
    const float r4 = fmaxf(s[4], 0.f), r5 = fmaxf(s[5], 0.f);
    const float r6 = fmaxf(s[6], 0.f), r7 = fmaxf(s[7], 0.f);
    float pa = r0 * u4a.x + r1 * u4a.y + r2 * u4a.z + r3 * u4a.w
             + r4 * u4b.x + r5 * u4b.y + r6 * u4b.z + r7 * u4b.w;
    float pb = r0 * v4a.x + r1 * v4a.y + r2 * v4a.z + r3 * v4a.w
             + r4 * v4b.x + r5 * v4b.y + r6 * v4b.z + r7 * v4b.w;

    #pragma unroll
    for (int m = 16; m; m >>= 1) {        // reduce within 32-lane half
        pa += __shfl_xor(pa, m);
        pb += __shfl_xor(pb, m);
    }
    if ((lane & 31) == 0) { av[node] = pa; bv[node] = pb; }
}

// ---------------------------------------------------------------------------
// 32 edges per wave: each 16-lane slot handles EIGHT edges (16 gathers in
// flight); fp8 z table (256 B/row, L2-resident); 2x float4 output stores.
// out = sigmoid(a[i] + b[j] + sum z_i z_j w3b / ZSCALE^2)
__global__ __launch_bounds__(256) void k_edge(
    const int* __restrict__ e1, const int* __restrict__ e2,
    const uint* __restrict__ zb8, const float* __restrict__ av,
    const float* __restrict__ bv, const float* __restrict__ W3,
    float* __restrict__ out)
{
    const long long wid = (((long long)blockIdx.x * blockDim.x) + threadIdx.x) >> 6;
    const int lane = threadIdx.x & 63;
    const int s16  = lane & 15;
    const long long e0 = 32LL * wid + ((lane >> 4) << 3);   // multiple of 8
    if (e0 >= 2LL * NE) return;                              // 2*NE % 32 == 0

    // per-lane w3b slice (16 f32), pre-scaled by 1/ZSCALE^2 (shared by 8 edges)
    const float* w3p = W3 + HID + (s16 << 4);
    f32x4 wv[4];
    #pragma unroll
    for (int i = 0; i < 4; ++i) {
        f32x4 t = *reinterpret_cast<const f32x4*>(w3p + (i << 2));
        wv[i] = t * ZSCINV;
    }

    int ii[8], jj[8];
    #pragma unroll
    for (int k = 0; k < 8; ++k) {
        const long long e = e0 + k;
        const int* ep = (e < NE) ? &e1[2 * (int)e] : &e2[2 * ((int)e - NE)];
        ii[k] = ep[0];
        jj[k] = ep[1];
    }

    // 16 independent dwordx4 gathers per slot
    i32x4 vi[8], vj[8];
    #pragma unroll
    for (int k = 0; k < 8; ++k) {
        vi[k] = *reinterpret_cast<const i32x4*>(&zb8[ii[k] * 64 + (s16 << 2)]);
        vj[k] = *reinterpret_cast<const i32x4*>(&zb8[jj[k] * 64 + (s16 << 2)]);
    }

    float p[8] = {0.f, 0.f, 0.f, 0.f, 0.f, 0.f, 0.f, 0.f};
    #pragma unroll
    for (int k = 0; k < 8; ++k) {
        #pragma unroll
        for (int qq = 0; qq < 4; ++qq) {
            const f32x2 il = __builtin_amdgcn_cvt_pk_f32_fp8(vi[k][qq], false);
            const f32x2 ih = __builtin_amdgcn_cvt_pk_f32_fp8(vi[k][qq], true);
            const f32x2 jl = __builtin_amdgcn_cvt_pk_f32_fp8(vj[k][qq], false);
            const f32x2 jh = __builtin_amdgcn_cvt_pk_f32_fp8(vj[k][qq], true);
            p[k] = fmaf(il.x * jl.x, wv[qq].x, p[k]);
            p[k] = fmaf(il.y * jl.y, wv[qq].y, p[k]);
            p[k] = fmaf(ih.x * jh.x, wv[qq].z, p[k]);
            p[k] = fmaf(ih.y * jh.y, wv[qq].w, p[k]);
        }
    }

    #pragma unroll
    for (int m = 8; m; m >>= 1) {
        #pragma unroll
        for (int k = 0; k < 8; ++k) p[k] += __shfl_xor(p[k], m);
    }

    if (s16 == 0) {
        f32x4 o0, o1;
        #pragma unroll
        for (int k = 0; k < 4; ++k) {
            const float lg = av[ii[k]] + bv[jj[k]] + p[k];
            o0[k] = 1.f / (1.f + expf(-lg));
        }
        #pragma unroll
        for (int k = 0; k < 4; ++k) {
            const float lg = av[ii[4 + k]] + bv[jj[4 + k]] + p[4 + k];
            o1[k] = 1.f / (1.f + expf(-lg));
        }
        *reinterpret_cast<f32x4*>(&out[e0])     = o0;
        *reinterpret_cast<f32x4*>(&out[e0 + 4]) = o1;
    }
}

// ---------------------------------------------------------------------------
extern "C" void kernel_launch(void* const* d_in, const int* in_sizes, int n_in,
                              void* d_out, int out_size, void* d_ws, size_t ws_size,
                              hipStream_t stream)
{
    const float* X   = (const float*)d_in[0];
    const float* adj = (const float*)d_in[1];
    const int*   e1  = (const int*)d_in[2];
    const int*   e2  = (const int*)d_in[3];
    const float* W   = (const float*)d_in[4];
    const float* W2  = (const float*)d_in[5];
    const float* W3  = (const float*)d_in[6];
    float* out = (float*)d_out;

    float*  ws    = (float*)d_ws;
    float*  a     = ws;                                  // NN
    float*  b     = a + NN;                              // NN
    float*  c     = b + NN;                              // 512
    ushort* Wt2   = (ushort*)(c + 512);                  // 16 panels * 8192
    ushort* XWt2  = Wt2  + (size_t)16 * 8192;            // 324 panels * 8192
    uint*   zb8   = (uint*)(XWt2 + (size_t)324 * 8192);  // NN*64 u32 (fp8 z)
    ushort* Cpart = (ushort*)(zb8 + (size_t)NN * 64);    // SKA*NN*HID bf16

    const dim3 blk(256);

    // fused: W -> tiled bf16 panels (blocks 0..15) + c = [u; v] (blocks 16..143)
    k_prep<<<dim3(144), blk, 0, stream>>>(W, Wt2, W2, W3, c);

    // XW panels = X @ W, fused panel epilogue; grid 81 covers 324 panels
    gemm_bt<true><<<dim3(81, 1), dim3(512), 0, stream>>>(
        X, Wt2, XWt2, NN, IND, IND, IND, 0);

    // Cpart = adj @ XW  (split-K = 6 -> 474 blocks, all co-resident)
    gemm_bt<false><<<dim3(79, SKA), dim3(512), 0, stream>>>(
        adj, XWt2, Cpart, NN, NN, NN, KCHA, (size_t)NN * HID);

    // reduce bf16 partials + fp8 z table + a,b  (2 nodes / wave)
    k_node<<<dim3((NN / 2 * 64) / 256), blk, 0, stream>>>(Cpart, c, zb8, a, b);

    // per-edge output (32 edges / wave, 8 per slot, 2x float4 stores)
    k_edge<<<dim3((2 * NE * 2) / 256), blk, 0, stream>>>(e1, e2, zb8, a, b, W3, out);
}